// Round 2
// baseline (727.877 us; speedup 1.0000x reference)
//
#include <hip/hip_runtime.h>
#include <cstdint>

// ---------------------------------------------------------------------------
// Attention_75093208203309 on gfx950 — round 2: 3-term split-precision chain.
// cl = q@C@k^T + bias decides a +/-10000 mask via sign(cl); every GEMM feeding
// cl uses A=[hi|lo|hi], B=[hi|hi|lo] (K=3072) giving ~2^-17 effective mantissa
// (drops only lo*lo). S and cl stored bf16 (sign-preserving; logit err ~0.006).
// Pipeline: prep -> G1 qkv -> G2 qc -> G3 [S;cl] -> mask+softmax -> G4 out.
// ---------------------------------------------------------------------------

typedef __attribute__((ext_vector_type(8))) short short8;
typedef __attribute__((ext_vector_type(4))) float f32x4;
typedef __attribute__((ext_vector_type(4))) float f4v;
typedef __attribute__((ext_vector_type(4))) unsigned short u16x4;
typedef __attribute__((ext_vector_type(8))) unsigned short u16x8;

typedef unsigned short u16;

__device__ __forceinline__ u16 f2bf(float f) {
  unsigned u = __float_as_uint(f);
  u += 0x7fffu + ((u >> 16) & 1u);   // RNE
  return (u16)(u >> 16);
}
__device__ __forceinline__ float bf2f(u16 h) {
  return __uint_as_float(((unsigned)h) << 16);
}

__device__ __forceinline__ void gld16(void* lds, const void* g) {
  __builtin_amdgcn_global_load_lds(
      (__attribute__((address_space(1))) void*)g,
      (__attribute__((address_space(3))) void*)lds,
      16, 0, 0);
}

// ---------------- prep kernels ----------------

// x [4096,1024] f32 -> xs3 [4096,3072] bf16 = [hi | lo | hi]   (A-side)
__global__ void prep_x(const float* __restrict__ x, u16* __restrict__ xs3) {
  int id = blockIdx.x * 256 + threadIdx.x;       // float4 index
  int flat = id * 4;
  int n = flat >> 10, i = flat & 1023;
  f4v v = *(const f4v*)(x + (size_t)flat);
  u16x4 hi, lo;
#pragma unroll
  for (int e = 0; e < 4; e++) {
    float f = v[e];
    u16 h = f2bf(f);
    hi[e] = h;
    lo[e] = f2bf(f - bf2f(h));
  }
  size_t base = (size_t)n * 3072 + i;
  *(u16x4*)(xs3 + base) = hi;
  *(u16x4*)(xs3 + base + 1024) = lo;
  *(u16x4*)(xs3 + base + 2048) = hi;
}

// W_{q,k,v} [1024,1024] -> W3 [3072 rows, 3072] bf16 = [hi | hi | lo]  (B-side)
__global__ void prep_w(const float* __restrict__ Wq, const float* __restrict__ Wk,
                       const float* __restrict__ Wv, u16* __restrict__ W3) {
  int id = blockIdx.x * 256 + threadIdx.x;
  int flat = id * 4;
  int o = flat >> 10, i = flat & 1023;
  const float* src = (o < 1024) ? (Wq + (size_t)o * 1024)
                   : (o < 2048) ? (Wk + (size_t)(o - 1024) * 1024)
                                : (Wv + (size_t)(o - 2048) * 1024);
  f4v v = *(const f4v*)(src + i);
  u16x4 hi, lo;
#pragma unroll
  for (int e = 0; e < 4; e++) {
    u16 h = f2bf(v[e]);
    hi[e] = h;
    lo[e] = f2bf(v[e] - bf2f(h));
  }
  size_t base = (size_t)o * 3072 + i;
  *(u16x4*)(W3 + base) = hi;
  *(u16x4*)(W3 + base + 1024) = hi;
  *(u16x4*)(W3 + base + 2048) = lo;
}

__global__ void prep_bias(const float* __restrict__ bq, const float* __restrict__ bk,
                          const float* __restrict__ bv, float* __restrict__ bp) {
  int id = blockIdx.x * 256 + threadIdx.x;
  float v = (id < 1024) ? bq[id] : (id < 2048) ? bk[id - 1024] : bv[id - 2048];
  bp[id] = v;
}

// connection C [1024,1024] -> C3 [1024,3072]: C3[j] = [Ct_hi | Ct_hi | Ct_lo],
// Ct[j][i] = C[i][j]   (B-side)
__global__ void prep_c(const float* __restrict__ C, u16* __restrict__ C3) {
  __shared__ float t[32][33];
  int lx = threadIdx.x & 31, ly = threadIdx.x >> 5;   // 32 x 8
  int i0 = blockIdx.x * 32, j0 = blockIdx.y * 32;
#pragma unroll
  for (int r = 0; r < 32; r += 8)
    t[ly + r][lx] = C[(size_t)(i0 + ly + r) * 1024 + j0 + lx];
  __syncthreads();
#pragma unroll
  for (int r = 0; r < 32; r += 8) {
    float f = t[lx][ly + r];                           // = C[i0+lx][j0+ly+r]
    u16 h = f2bf(f);
    u16 l = f2bf(f - bf2f(h));
    size_t o = (size_t)(j0 + ly + r) * 3072 + i0 + lx;
    C3[o] = h;
    C3[o + 1024] = h;
    C3[o + 2048] = l;
  }
}

// ---------------- NT GEMM (m97 structure) ----------------
// C[M,N] = A[M,K] @ B[N,K]^T, bf16 in, fp32 accum, 128x128 tile, 4 waves,
// 16x16x32 bf16 MFMA, global_load_lds width 16.

struct EpiQKV {       // G1: columns [0,1024)=q, [1024,2048)=k, [2048,3072)=v
  const float* bp; u16* qs3; u16* k3; u16* vt;
  __device__ void operator()(int r, int c, float v) const {
    v += bp[c];
    u16 h = f2bf(v);
    u16 l = f2bf(v - bf2f(h));
    if (c < 1024) {                       // q: A-side [hi|lo|hi]
      size_t b = (size_t)r * 3072 + c;
      qs3[b] = h; qs3[b + 1024] = l; qs3[b + 2048] = h;
    } else if (c < 2048) {                // k: B-side [hi|hi|lo]
      size_t b = (size_t)r * 3072 + (c - 1024);
      k3[b] = h; k3[b + 1024] = h; k3[b + 2048] = l;
    } else {                              // v: transposed, single bf16
      vt[(size_t)(c - 2048) * 4096 + r] = h;
    }
  }
};

struct EpiQC {        // G2: qc A-side [hi|lo|hi]
  u16* qc3;
  __device__ void operator()(int r, int c, float v) const {
    u16 h = f2bf(v);
    u16 l = f2bf(v - bf2f(h));
    size_t b = (size_t)r * 3072 + c;
    qc3[b] = h; qc3[b + 1024] = l; qc3[b + 2048] = h;
  }
};

struct EpiSbf {       // G3: store bf16 (sign-preserving for cl rows)
  u16* sc;
  __device__ void operator()(int r, int c, float v) const {
    sc[(size_t)r * 4096 + c] = f2bf(v);
  }
};

struct EpiOut {       // G4: boundary blend
  const float* x; const float* bm; float* out;
  __device__ void operator()(int r, int c, float v) const {
    float b = bm[r];
    out[(size_t)r * 1024 + c] = b * v + (1.0f - b) * x[(size_t)r * 1024 + c];
  }
};

template <class Epi>
__global__ __launch_bounds__(256, 2) void gemm_nt(
    const u16* __restrict__ A, const u16* __restrict__ B,
    int lda, int ldb, int K, Epi epi) {
  __shared__ __align__(16) u16 lA[128 * 32];
  __shared__ __align__(16) u16 lB[128 * 32];
  const int tid = threadIdx.x;
  const int mBase = blockIdx.y * 128, nBase = blockIdx.x * 128;
  const int wave = tid >> 6, lane = tid & 63;
  const int wm = wave & 1, wn = wave >> 1;
  const int lane16 = lane & 15, quad = lane >> 4;

  const u16* a0 = A + (size_t)(mBase + (tid >> 2)) * lda + (tid & 3) * 8;
  const u16* a1 = a0 + (size_t)64 * lda;
  const u16* b0 = B + (size_t)(nBase + (tid >> 2)) * ldb + (tid & 3) * 8;
  const u16* b1 = b0 + (size_t)64 * ldb;

  char* lAb = (char*)lA + wave * 1024;   // wave-uniform LDS staging bases
  char* lBb = (char*)lB + wave * 1024;

  const u16* ra = lA + (wm * 64 + lane16) * 32 + quad * 8;
  const u16* rb = lB + (wn * 64 + lane16) * 32 + quad * 8;

  f32x4 acc[4][4];
#pragma unroll
  for (int i = 0; i < 4; i++)
#pragma unroll
    for (int j = 0; j < 4; j++) acc[i][j] = (f32x4){0.f, 0.f, 0.f, 0.f};

  for (int k0 = 0; k0 < K; k0 += 32) {
    gld16(lAb,        a0 + k0);
    gld16(lAb + 4096, a1 + k0);
    gld16(lBb,        b0 + k0);
    gld16(lBb + 4096, b1 + k0);
    __syncthreads();
    short8 af[4], bfr[4];
#pragma unroll
    for (int i = 0; i < 4; i++) af[i] = *(const short8*)(ra + i * 16 * 32);
#pragma unroll
    for (int i = 0; i < 4; i++) bfr[i] = *(const short8*)(rb + i * 16 * 32);
#pragma unroll
    for (int im = 0; im < 4; im++)
#pragma unroll
      for (int in = 0; in < 4; in++)
        acc[im][in] = __builtin_amdgcn_mfma_f32_16x16x32_bf16(af[im], bfr[in], acc[im][in], 0, 0, 0);
    __syncthreads();
  }

#pragma unroll
  for (int im = 0; im < 4; im++)
#pragma unroll
    for (int in = 0; in < 4; in++)
#pragma unroll
      for (int i = 0; i < 4; i++) {
        int r = mBase + wm * 64 + im * 16 + quad * 4 + i;
        int c = nBase + wn * 64 + in * 16 + lane16;
        epi(r, c, acc[im][in][i]);
      }
}

// ---------------- mask + softmax ----------------
// One block per row. logits = S/32 - 10000*(1 - am - (cl+bias>0)*lm).
__global__ __launch_bounds__(256) void mask_softmax(
    const u16* __restrict__ Sc, const float* __restrict__ am,
    const float* __restrict__ lm, const float* __restrict__ bias,
    u16* __restrict__ P) {
  const int n = blockIdx.x, tid = threadIdx.x;
  const int lane = tid & 63, wave = tid >> 6;
  const float b0 = bias[0];
  const u16* Srow = Sc + (size_t)n * 4096;
  const u16* Crow = Sc + (size_t)(4096 + n) * 4096;
  const float* Arow = am + (size_t)n * 4096;
  const float* Lrow = lm + (size_t)n * 4096;

  float lg[16];
  float mx = -3.4e38f;
#pragma unroll
  for (int j = 0; j < 2; j++) {
    int base = (tid + 256 * j) * 8;
    u16x8 s8 = *(const u16x8*)(Srow + base);
    u16x8 c8 = *(const u16x8*)(Crow + base);
    f4v a0 = *(const f4v*)(Arow + base), a1 = *(const f4v*)(Arow + base + 4);
    f4v l0 = *(const f4v*)(Lrow + base), l1 = *(const f4v*)(Lrow + base + 4);
#pragma unroll
    for (int e = 0; e < 8; e++) {
      float st = (bf2f(c8[e]) + b0 > 0.f) ? 1.f : 0.f;
      float a = (e < 4) ? a0[e] : a1[e - 4];
      float l = (e < 4) ? l0[e] : l1[e - 4];
      float mv = a + st * l;
      float v = bf2f(s8[e]) * 0.03125f - 10000.f * (1.f - mv);
      lg[j * 8 + e] = v;
      mx = fmaxf(mx, v);
    }
  }
#pragma unroll
  for (int o = 32; o; o >>= 1) mx = fmaxf(mx, __shfl_xor(mx, o));
  __shared__ float smax[4], ssum[4];
  if (lane == 0) smax[wave] = mx;
  __syncthreads();
  mx = fmaxf(fmaxf(smax[0], smax[1]), fmaxf(smax[2], smax[3]));

  float sum = 0.f;
#pragma unroll
  for (int i = 0; i < 16; i++) { lg[i] = __expf(lg[i] - mx); sum += lg[i]; }
#pragma unroll
  for (int o = 32; o; o >>= 1) sum += __shfl_xor(sum, o);
  if (lane == 0) ssum[wave] = sum;
  __syncthreads();
  float inv = 1.f / (ssum[0] + ssum[1] + ssum[2] + ssum[3]);

  u16* Pr = P + (size_t)n * 4096;
#pragma unroll
  for (int j = 0; j < 2; j++) {
    int base = (tid + 256 * j) * 8;
    u16x8 o8;
#pragma unroll
    for (int e = 0; e < 8; e++) o8[e] = f2bf(lg[j * 8 + e] * inv);
    *(u16x8*)(Pr + base) = o8;
  }
}

// ---------------- launch ----------------

extern "C" void kernel_launch(void* const* d_in, const int* in_sizes, int n_in,
                              void* d_out, int out_size, void* d_ws, size_t ws_size,
                              hipStream_t stream) {
  const float* x    = (const float*)d_in[0];
  const float* am   = (const float*)d_in[1];
  const float* lm   = (const float*)d_in[2];
  const float* bm   = (const float*)d_in[3];
  const float* Wq   = (const float*)d_in[4];
  const float* bq   = (const float*)d_in[5];
  const float* Wk   = (const float*)d_in[6];
  const float* bk   = (const float*)d_in[7];
  const float* Wv   = (const float*)d_in[8];
  const float* bv   = (const float*)d_in[9];
  const float* Cc   = (const float*)d_in[10];
  const float* bias = (const float*)d_in[11];
  float* out = (float*)d_out;
  char* ws = (char*)d_ws;

  if (ws_size < 0xC010000) return;  // ~201 MB scratch

  u16*  xs3 = (u16*) (ws + 0x0000000);  // 24 MB [x_hi|x_lo|x_hi]
  u16*  W3  = (u16*) (ws + 0x1800000);  // 18 MB [W_hi|W_hi|W_lo] (q,k,v rows)
  u16*  C3  = (u16*) (ws + 0x2A00000);  //  6 MB [Ct_hi|Ct_hi|Ct_lo]
  float* bp = (float*)(ws + 0x3000000); // 12 KB
  u16*  qs3 = (u16*) (ws + 0x3010000);  // 24 MB [q_hi|q_lo|q_hi]
  u16*  qc3 = (u16*) (ws + 0x4810000);  // 24 MB [qc_hi|qc_lo|qc_hi] (contig after qs3)
  u16*  k3  = (u16*) (ws + 0x6010000);  // 24 MB [k_hi|k_hi|k_lo]
  u16*  vt  = (u16*) (ws + 0x7810000);  //  8 MB v^T [1024,4096]
  u16*  Sc  = (u16*) (ws + 0x8010000);  // 64 MB bf16 [S rows 0..4095 ; cl rows 4096..8191]
  u16*  P   = (u16*) (ws + 0x0000000);  // 32 MB overlay (xs3/W3 dead by softmax)

  prep_x   <<<4096, 256, 0, stream>>>(x, xs3);
  prep_w   <<<3072, 256, 0, stream>>>(Wq, Wk, Wv, W3);
  prep_bias<<<12,   256, 0, stream>>>(bq, bk, bv, bp);
  prep_c   <<<dim3(32, 32), 256, 0, stream>>>(Cc, C3);

  // G1: qkv = xs3 @ W3^T   (M=4096, N=3072, K=3072)
  gemm_nt<<<dim3(24, 32), 256, 0, stream>>>(xs3, W3, 3072, 3072, 3072,
                                            EpiQKV{bp, qs3, k3, vt});
  // G2: qc = qs3 @ C3^T    (M=4096, N=1024, K=3072)
  gemm_nt<<<dim3(8, 32), 256, 0, stream>>>(qs3, C3, 3072, 3072, 3072,
                                           EpiQC{qc3});
  // G3: [S;cl] = [qs3;qc3] @ k3^T  (M=8192, N=4096, K=3072)
  gemm_nt<<<dim3(32, 64), 256, 0, stream>>>(qs3, k3, 3072, 3072, 3072,
                                            EpiSbf{Sc});
  // mask + softmax -> P (bf16)
  mask_softmax<<<4096, 256, 0, stream>>>(Sc, am, lm, bias, P);
  // G4: out = P @ vt^T  (M=4096, N=1024, K=4096) + boundary blend
  gemm_nt<<<dim3(8, 32), 256, 0, stream>>>(P, vt, 4096, 4096, 4096,
                                           EpiOut{x, bm, out});
}

// Round 3
// 650.773 us; speedup vs baseline: 1.1185x; 1.1185x over previous
//
#include <hip/hip_runtime.h>
#include <cstdint>

// ---------------------------------------------------------------------------
// Attention_75093208203309 on gfx950 — round 3.
// vs R2: (1) XOR-swizzled LDS layout in gemm_nt kills the 8-way ds_read_b128
// bank conflicts (2.5e7 conflict cycles ~ 15% of CU time); (2) G3 split into
// S = q_hi @ k_hi^T (K=1024) and CL = qc3 @ k3^T (K=3072) — S doesn't need the
// 3-term split (logit error 0.003), saving 69 GF.
// Pipeline: prep -> G1 qkv -> G2 qc -> S -> CL -> mask+softmax -> G4 out.
// ---------------------------------------------------------------------------

typedef __attribute__((ext_vector_type(8))) short short8;
typedef __attribute__((ext_vector_type(4))) float f32x4;
typedef __attribute__((ext_vector_type(4))) float f4v;
typedef __attribute__((ext_vector_type(4))) unsigned short u16x4;
typedef __attribute__((ext_vector_type(8))) unsigned short u16x8;

typedef unsigned short u16;

__device__ __forceinline__ u16 f2bf(float f) {
  unsigned u = __float_as_uint(f);
  u += 0x7fffu + ((u >> 16) & 1u);   // RNE
  return (u16)(u >> 16);
}
__device__ __forceinline__ float bf2f(u16 h) {
  return __uint_as_float(((unsigned)h) << 16);
}

__device__ __forceinline__ void gld16(void* lds, const void* g) {
  __builtin_amdgcn_global_load_lds(
      (__attribute__((address_space(1))) void*)g,
      (__attribute__((address_space(3))) void*)lds,
      16, 0, 0);
}

// ---------------- prep kernels ----------------

// x [4096,1024] f32 -> xs3 [4096,3072] bf16 = [hi | lo | hi]   (A-side)
__global__ void prep_x(const float* __restrict__ x, u16* __restrict__ xs3) {
  int id = blockIdx.x * 256 + threadIdx.x;       // float4 index
  int flat = id * 4;
  int n = flat >> 10, i = flat & 1023;
  f4v v = *(const f4v*)(x + (size_t)flat);
  u16x4 hi, lo;
#pragma unroll
  for (int e = 0; e < 4; e++) {
    float f = v[e];
    u16 h = f2bf(f);
    hi[e] = h;
    lo[e] = f2bf(f - bf2f(h));
  }
  size_t base = (size_t)n * 3072 + i;
  *(u16x4*)(xs3 + base) = hi;
  *(u16x4*)(xs3 + base + 1024) = lo;
  *(u16x4*)(xs3 + base + 2048) = hi;
}

// W_{q,k,v} [1024,1024] -> W3 [3072 rows, 3072] bf16 = [hi | hi | lo]  (B-side)
__global__ void prep_w(const float* __restrict__ Wq, const float* __restrict__ Wk,
                       const float* __restrict__ Wv, u16* __restrict__ W3) {
  int id = blockIdx.x * 256 + threadIdx.x;
  int flat = id * 4;
  int o = flat >> 10, i = flat & 1023;
  const float* src = (o < 1024) ? (Wq + (size_t)o * 1024)
                   : (o < 2048) ? (Wk + (size_t)(o - 1024) * 1024)
                                : (Wv + (size_t)(o - 2048) * 1024);
  f4v v = *(const f4v*)(src + i);
  u16x4 hi, lo;
#pragma unroll
  for (int e = 0; e < 4; e++) {
    u16 h = f2bf(v[e]);
    hi[e] = h;
    lo[e] = f2bf(v[e] - bf2f(h));
  }
  size_t base = (size_t)o * 3072 + i;
  *(u16x4*)(W3 + base) = hi;
  *(u16x4*)(W3 + base + 1024) = hi;
  *(u16x4*)(W3 + base + 2048) = lo;
}

__global__ void prep_bias(const float* __restrict__ bq, const float* __restrict__ bk,
                          const float* __restrict__ bv, float* __restrict__ bp) {
  int id = blockIdx.x * 256 + threadIdx.x;
  float v = (id < 1024) ? bq[id] : (id < 2048) ? bk[id - 1024] : bv[id - 2048];
  bp[id] = v;
}

// connection C [1024,1024] -> C3 [1024,3072]: C3[j] = [Ct_hi | Ct_hi | Ct_lo],
// Ct[j][i] = C[i][j]   (B-side)
__global__ void prep_c(const float* __restrict__ C, u16* __restrict__ C3) {
  __shared__ float t[32][33];
  int lx = threadIdx.x & 31, ly = threadIdx.x >> 5;   // 32 x 8
  int i0 = blockIdx.x * 32, j0 = blockIdx.y * 32;
#pragma unroll
  for (int r = 0; r < 32; r += 8)
    t[ly + r][lx] = C[(size_t)(i0 + ly + r) * 1024 + j0 + lx];
  __syncthreads();
#pragma unroll
  for (int r = 0; r < 32; r += 8) {
    float f = t[lx][ly + r];                           // = C[i0+lx][j0+ly+r]
    u16 h = f2bf(f);
    u16 l = f2bf(f - bf2f(h));
    size_t o = (size_t)(j0 + ly + r) * 3072 + i0 + lx;
    C3[o] = h;
    C3[o + 1024] = h;
    C3[o + 2048] = l;
  }
}

// ---------------- NT GEMM (m97 structure + XOR bank swizzle) ----------------
// C[M,N] = A[M,K] @ B[N,K]^T, bf16 in, fp32 accum, 128x128 tile, 4 waves,
// 16x16x32 bf16 MFMA, global_load_lds width 16.
// LDS layout: row r's 8-elem k-chunk c lives at physical slot c ^ ((r>>1)&3).
// Staging lane can't choose its LDS slot (wave-uniform base + lane*16), so it
// chooses WHICH global chunk to fetch instead; reader XORs the same term.
// Result: ds_read_b128 hits each bank exactly 8 dwords -> zero conflicts.

struct EpiQKV {       // G1: columns [0,1024)=q, [1024,2048)=k, [2048,3072)=v
  const float* bp; u16* qs3; u16* k3; u16* vt;
  __device__ void operator()(int r, int c, float v) const {
    v += bp[c];
    u16 h = f2bf(v);
    u16 l = f2bf(v - bf2f(h));
    if (c < 1024) {                       // q: A-side [hi|lo|hi]
      size_t b = (size_t)r * 3072 + c;
      qs3[b] = h; qs3[b + 1024] = l; qs3[b + 2048] = h;
    } else if (c < 2048) {                // k: B-side [hi|hi|lo]
      size_t b = (size_t)r * 3072 + (c - 1024);
      k3[b] = h; k3[b + 1024] = h; k3[b + 2048] = l;
    } else {                              // v: transposed, single bf16
      vt[(size_t)(c - 2048) * 4096 + r] = h;
    }
  }
};

struct EpiQC {        // G2: qc A-side [hi|lo|hi]
  u16* qc3;
  __device__ void operator()(int r, int c, float v) const {
    u16 h = f2bf(v);
    u16 l = f2bf(v - bf2f(h));
    size_t b = (size_t)r * 3072 + c;
    qc3[b] = h; qc3[b + 1024] = l; qc3[b + 2048] = h;
  }
};

struct EpiSbf {       // S / CL: store bf16 (sign-preserving for cl)
  u16* sc;
  __device__ void operator()(int r, int c, float v) const {
    sc[(size_t)r * 4096 + c] = f2bf(v);
  }
};

struct EpiOut {       // G4: boundary blend
  const float* x; const float* bm; float* out;
  __device__ void operator()(int r, int c, float v) const {
    float b = bm[r];
    out[(size_t)r * 1024 + c] = b * v + (1.0f - b) * x[(size_t)r * 1024 + c];
  }
};

template <class Epi>
__global__ __launch_bounds__(256, 2) void gemm_nt(
    const u16* __restrict__ A, const u16* __restrict__ B,
    int lda, int ldb, int K, Epi epi) {
  __shared__ __align__(16) u16 lA[128 * 32];
  __shared__ __align__(16) u16 lB[128 * 32];
  const int tid = threadIdx.x;
  const int mBase = blockIdx.y * 128, nBase = blockIdx.x * 128;
  const int wave = tid >> 6, lane = tid & 63;
  const int wm = wave & 1, wn = wave >> 1;
  const int lane16 = lane & 15, quad = lane >> 4;

  // staging: thread stages row (tid>>2); physical slot (tid&3) must hold
  // data chunk (tid&3) ^ swizzle(row), swizzle(row) = (row>>1)&3 = (tid>>3)&3
  const int ssw = (tid >> 3) & 3;
  const int chunk = ((tid & 3) ^ ssw) * 8;
  const u16* a0 = A + (size_t)(mBase + (tid >> 2)) * lda + chunk;
  const u16* a1 = a0 + (size_t)64 * lda;     // row+64: swizzle unchanged
  const u16* b0 = B + (size_t)(nBase + (tid >> 2)) * ldb + chunk;
  const u16* b1 = b0 + (size_t)64 * ldb;

  char* lAb = (char*)lA + wave * 1024;   // wave-uniform LDS staging bases
  char* lBb = (char*)lB + wave * 1024;

  // read: fragment rows lane16 + 16i (+64*wm/wn): swizzle = (lane16>>1)&3
  const int rsw = (lane16 >> 1) & 3;
  const u16* ra = lA + (wm * 64 + lane16) * 32 + (quad ^ rsw) * 8;
  const u16* rb = lB + (wn * 64 + lane16) * 32 + (quad ^ rsw) * 8;

  f32x4 acc[4][4];
#pragma unroll
  for (int i = 0; i < 4; i++)
#pragma unroll
    for (int j = 0; j < 4; j++) acc[i][j] = (f32x4){0.f, 0.f, 0.f, 0.f};

  for (int k0 = 0; k0 < K; k0 += 32) {
    gld16(lAb,        a0 + k0);
    gld16(lAb + 4096, a1 + k0);
    gld16(lBb,        b0 + k0);
    gld16(lBb + 4096, b1 + k0);
    __syncthreads();
    short8 af[4], bfr[4];
#pragma unroll
    for (int i = 0; i < 4; i++) af[i] = *(const short8*)(ra + i * 16 * 32);
#pragma unroll
    for (int i = 0; i < 4; i++) bfr[i] = *(const short8*)(rb + i * 16 * 32);
#pragma unroll
    for (int im = 0; im < 4; im++)
#pragma unroll
      for (int in = 0; in < 4; in++)
        acc[im][in] = __builtin_amdgcn_mfma_f32_16x16x32_bf16(af[im], bfr[in], acc[im][in], 0, 0, 0);
    __syncthreads();
  }

#pragma unroll
  for (int im = 0; im < 4; im++)
#pragma unroll
    for (int in = 0; in < 4; in++)
#pragma unroll
      for (int i = 0; i < 4; i++) {
        int r = mBase + wm * 64 + im * 16 + quad * 4 + i;
        int c = nBase + wn * 64 + in * 16 + lane16;
        epi(r, c, acc[im][in][i]);
      }
}

// ---------------- mask + softmax ----------------
// One block per row. logits = S/32 - 10000*(1 - am - (cl+bias>0)*lm).
__global__ __launch_bounds__(256) void mask_softmax(
    const u16* __restrict__ Sc, const float* __restrict__ am,
    const float* __restrict__ lm, const float* __restrict__ bias,
    u16* __restrict__ P) {
  const int n = blockIdx.x, tid = threadIdx.x;
  const int lane = tid & 63, wave = tid >> 6;
  const float b0 = bias[0];
  const u16* Srow = Sc + (size_t)n * 4096;
  const u16* Crow = Sc + (size_t)(4096 + n) * 4096;
  const float* Arow = am + (size_t)n * 4096;
  const float* Lrow = lm + (size_t)n * 4096;

  float lg[16];
  float mx = -3.4e38f;
#pragma unroll
  for (int j = 0; j < 2; j++) {
    int base = (tid + 256 * j) * 8;
    u16x8 s8 = *(const u16x8*)(Srow + base);
    u16x8 c8 = *(const u16x8*)(Crow + base);
    f4v a0 = *(const f4v*)(Arow + base), a1 = *(const f4v*)(Arow + base + 4);
    f4v l0 = *(const f4v*)(Lrow + base), l1 = *(const f4v*)(Lrow + base + 4);
#pragma unroll
    for (int e = 0; e < 8; e++) {
      float st = (bf2f(c8[e]) + b0 > 0.f) ? 1.f : 0.f;
      float a = (e < 4) ? a0[e] : a1[e - 4];
      float l = (e < 4) ? l0[e] : l1[e - 4];
      float mv = a + st * l;
      float v = bf2f(s8[e]) * 0.03125f - 10000.f * (1.f - mv);
      lg[j * 8 + e] = v;
      mx = fmaxf(mx, v);
    }
  }
#pragma unroll
  for (int o = 32; o; o >>= 1) mx = fmaxf(mx, __shfl_xor(mx, o));
  __shared__ float smax[4], ssum[4];
  if (lane == 0) smax[wave] = mx;
  __syncthreads();
  mx = fmaxf(fmaxf(smax[0], smax[1]), fmaxf(smax[2], smax[3]));

  float sum = 0.f;
#pragma unroll
  for (int i = 0; i < 16; i++) { lg[i] = __expf(lg[i] - mx); sum += lg[i]; }
#pragma unroll
  for (int o = 32; o; o >>= 1) sum += __shfl_xor(sum, o);
  if (lane == 0) ssum[wave] = sum;
  __syncthreads();
  float inv = 1.f / (ssum[0] + ssum[1] + ssum[2] + ssum[3]);

  u16* Pr = P + (size_t)n * 4096;
#pragma unroll
  for (int j = 0; j < 2; j++) {
    int base = (tid + 256 * j) * 8;
    u16x8 o8;
#pragma unroll
    for (int e = 0; e < 8; e++) o8[e] = f2bf(lg[j * 8 + e] * inv);
    *(u16x8*)(Pr + base) = o8;
  }
}

// ---------------- launch ----------------

extern "C" void kernel_launch(void* const* d_in, const int* in_sizes, int n_in,
                              void* d_out, int out_size, void* d_ws, size_t ws_size,
                              hipStream_t stream) {
  const float* x    = (const float*)d_in[0];
  const float* am   = (const float*)d_in[1];
  const float* lm   = (const float*)d_in[2];
  const float* bm   = (const float*)d_in[3];
  const float* Wq   = (const float*)d_in[4];
  const float* bq   = (const float*)d_in[5];
  const float* Wk   = (const float*)d_in[6];
  const float* bk   = (const float*)d_in[7];
  const float* Wv   = (const float*)d_in[8];
  const float* bv   = (const float*)d_in[9];
  const float* Cc   = (const float*)d_in[10];
  const float* bias = (const float*)d_in[11];
  float* out = (float*)d_out;
  char* ws = (char*)d_ws;

  if (ws_size < 0xC010000) return;  // ~201 MB scratch

  u16*  xs3 = (u16*) (ws + 0x0000000);  // 24 MB [x_hi|x_lo|x_hi]
  u16*  W3  = (u16*) (ws + 0x1800000);  // 18 MB [W_hi|W_hi|W_lo] (q,k,v rows)
  u16*  C3  = (u16*) (ws + 0x2A00000);  //  6 MB [Ct_hi|Ct_hi|Ct_lo]
  float* bp = (float*)(ws + 0x3000000); // 12 KB
  u16*  qs3 = (u16*) (ws + 0x3010000);  // 24 MB [q_hi|q_lo|q_hi]
  u16*  qc3 = (u16*) (ws + 0x4810000);  // 24 MB [qc_hi|qc_lo|qc_hi]
  u16*  k3  = (u16*) (ws + 0x6010000);  // 24 MB [k_hi|k_hi|k_lo]
  u16*  vt  = (u16*) (ws + 0x7810000);  //  8 MB v^T [1024,4096]
  u16*  Sc  = (u16*) (ws + 0x8010000);  // 64 MB bf16 [S rows 0..4095 ; cl rows 4096..8191]
  u16*  P   = (u16*) (ws + 0x0000000);  // 32 MB overlay (xs3/W3 dead by softmax)

  prep_x   <<<4096, 256, 0, stream>>>(x, xs3);
  prep_w   <<<3072, 256, 0, stream>>>(Wq, Wk, Wv, W3);
  prep_bias<<<12,   256, 0, stream>>>(bq, bk, bv, bp);
  prep_c   <<<dim3(32, 32), 256, 0, stream>>>(Cc, C3);

  // G1: qkv = xs3 @ W3^T   (M=4096, N=3072, K=3072)
  gemm_nt<<<dim3(24, 32), 256, 0, stream>>>(xs3, W3, 3072, 3072, 3072,
                                            EpiQKV{bp, qs3, k3, vt});
  // G2: qc = qs3 @ C3^T    (M=4096, N=1024, K=3072)
  gemm_nt<<<dim3(8, 32), 256, 0, stream>>>(qs3, C3, 3072, 3072, 3072,
                                           EpiQC{qc3});
  // S = q_hi @ k_hi^T      (M=4096, N=4096, K=1024) -> Sc rows 0..4095
  gemm_nt<<<dim3(32, 32), 256, 0, stream>>>(qs3, k3, 3072, 3072, 1024,
                                            EpiSbf{Sc});
  // CL = qc3 @ k3^T        (M=4096, N=4096, K=3072) -> Sc rows 4096..8191
  gemm_nt<<<dim3(32, 32), 256, 0, stream>>>(qc3, k3, 3072, 3072, 3072,
                                            EpiSbf{Sc + (size_t)4096 * 4096});
  // mask + softmax -> P (bf16)
  mask_softmax<<<4096, 256, 0, stream>>>(Sc, am, lm, bias, P);
  // G4: out = P @ vt^T  (M=4096, N=1024, K=4096) + boundary blend
  gemm_nt<<<dim3(8, 32), 256, 0, stream>>>(P, vt, 4096, 4096, 4096,
                                           EpiOut{x, bm, out});
}

// Round 4
// 587.031 us; speedup vs baseline: 1.2399x; 1.1086x over previous
//
#include <hip/hip_runtime.h>
#include <cstdint>

// ---------------------------------------------------------------------------
// Attention_75093208203309 on gfx950 — round 4.
// vs R3: (1) BK=64 K-step (32 KB LDS): halves barrier-drain count, 32 MFMA
// per barrier pair; XOR swizzle slot = chunk ^ (row&7) keeps LDS conflict-free
// under the lane-linear global_load_lds constraint. (2) G2 (qc) and S (q@k^T)
// merged into one 1280-block dispatch — they're independent after G1, and
// stream order would serialize them (G2 alone is 1 block/CU, latency-bound).
// Pipeline: prep -> G1 qkv -> [G2|S] -> CL -> mask+softmax -> G4 out.
// ---------------------------------------------------------------------------

typedef __attribute__((ext_vector_type(8))) short short8;
typedef __attribute__((ext_vector_type(4))) float f32x4;
typedef __attribute__((ext_vector_type(4))) float f4v;
typedef __attribute__((ext_vector_type(4))) unsigned short u16x4;
typedef __attribute__((ext_vector_type(8))) unsigned short u16x8;

typedef unsigned short u16;

__device__ __forceinline__ u16 f2bf(float f) {
  unsigned u = __float_as_uint(f);
  u += 0x7fffu + ((u >> 16) & 1u);   // RNE
  return (u16)(u >> 16);
}
__device__ __forceinline__ float bf2f(u16 h) {
  return __uint_as_float(((unsigned)h) << 16);
}

__device__ __forceinline__ void gld16(void* lds, const void* g) {
  __builtin_amdgcn_global_load_lds(
      (__attribute__((address_space(1))) void*)g,
      (__attribute__((address_space(3))) void*)lds,
      16, 0, 0);
}

// ---------------- prep kernels ----------------

// x [4096,1024] f32 -> xs3 [4096,3072] bf16 = [hi | lo | hi]   (A-side)
__global__ void prep_x(const float* __restrict__ x, u16* __restrict__ xs3) {
  int id = blockIdx.x * 256 + threadIdx.x;       // float4 index
  int flat = id * 4;
  int n = flat >> 10, i = flat & 1023;
  f4v v = *(const f4v*)(x + (size_t)flat);
  u16x4 hi, lo;
#pragma unroll
  for (int e = 0; e < 4; e++) {
    float f = v[e];
    u16 h = f2bf(f);
    hi[e] = h;
    lo[e] = f2bf(f - bf2f(h));
  }
  size_t base = (size_t)n * 3072 + i;
  *(u16x4*)(xs3 + base) = hi;
  *(u16x4*)(xs3 + base + 1024) = lo;
  *(u16x4*)(xs3 + base + 2048) = hi;
}

// W_{q,k,v} [1024,1024] -> W3 [3072 rows, 3072] bf16 = [hi | hi | lo]  (B-side)
__global__ void prep_w(const float* __restrict__ Wq, const float* __restrict__ Wk,
                       const float* __restrict__ Wv, u16* __restrict__ W3) {
  int id = blockIdx.x * 256 + threadIdx.x;
  int flat = id * 4;
  int o = flat >> 10, i = flat & 1023;
  const float* src = (o < 1024) ? (Wq + (size_t)o * 1024)
                   : (o < 2048) ? (Wk + (size_t)(o - 1024) * 1024)
                                : (Wv + (size_t)(o - 2048) * 1024);
  f4v v = *(const f4v*)(src + i);
  u16x4 hi, lo;
#pragma unroll
  for (int e = 0; e < 4; e++) {
    u16 h = f2bf(v[e]);
    hi[e] = h;
    lo[e] = f2bf(v[e] - bf2f(h));
  }
  size_t base = (size_t)o * 3072 + i;
  *(u16x4*)(W3 + base) = hi;
  *(u16x4*)(W3 + base + 1024) = hi;
  *(u16x4*)(W3 + base + 2048) = lo;
}

__global__ void prep_bias(const float* __restrict__ bq, const float* __restrict__ bk,
                          const float* __restrict__ bv, float* __restrict__ bp) {
  int id = blockIdx.x * 256 + threadIdx.x;
  float v = (id < 1024) ? bq[id] : (id < 2048) ? bk[id - 1024] : bv[id - 2048];
  bp[id] = v;
}

// connection C [1024,1024] -> C3 [1024,3072]: C3[j] = [Ct_hi | Ct_hi | Ct_lo]
__global__ void prep_c(const float* __restrict__ C, u16* __restrict__ C3) {
  __shared__ float t[32][33];
  int lx = threadIdx.x & 31, ly = threadIdx.x >> 5;   // 32 x 8
  int i0 = blockIdx.x * 32, j0 = blockIdx.y * 32;
#pragma unroll
  for (int r = 0; r < 32; r += 8)
    t[ly + r][lx] = C[(size_t)(i0 + ly + r) * 1024 + j0 + lx];
  __syncthreads();
#pragma unroll
  for (int r = 0; r < 32; r += 8) {
    float f = t[lx][ly + r];                           // = C[i0+lx][j0+ly+r]
    u16 h = f2bf(f);
    u16 l = f2bf(f - bf2f(h));
    size_t o = (size_t)(j0 + ly + r) * 3072 + i0 + lx;
    C3[o] = h;
    C3[o + 1024] = h;
    C3[o + 2048] = l;
  }
}

// ---------------- NT GEMM core, BK=64 + XOR bank swizzle ----------------
// C[M,N] = A[M,K] @ B[N,K]^T, bf16 in, fp32 accum, 128x128 tile, 4 waves,
// 16x16x32 bf16 MFMA, global_load_lds width 16, 64-deep K-step.
// LDS: row-major [128 rows][8 slots of 8 elems], row stride 128 B (=32 banks).
// Row r's k-chunk c lives at slot c ^ (r&7); staging thread t fetches global
// chunk (t&7)^((t>>3)&7) so the HW's lane-linear LDS write lands it right;
// reader uses slot ((4s+quad) ^ (lane16&7)). Uniform 8 dwords/bank -> 0 confl.

struct EpiQKV {       // G1: columns [0,1024)=q, [1024,2048)=k, [2048,3072)=v
  const float* bp; u16* qs3; u16* k3; u16* vt;
  __device__ void operator()(int r, int c, float v) const {
    v += bp[c];
    u16 h = f2bf(v);
    u16 l = f2bf(v - bf2f(h));
    if (c < 1024) {                       // q: A-side [hi|lo|hi]
      size_t b = (size_t)r * 3072 + c;
      qs3[b] = h; qs3[b + 1024] = l; qs3[b + 2048] = h;
    } else if (c < 2048) {                // k: B-side [hi|hi|lo]
      size_t b = (size_t)r * 3072 + (c - 1024);
      k3[b] = h; k3[b + 1024] = h; k3[b + 2048] = l;
    } else {                              // v: transposed, single bf16
      vt[(size_t)(c - 2048) * 4096 + r] = h;
    }
  }
};

struct EpiQCS {       // merged G2/S epilogue
  u16* qc3; u16* Sc; int isS;
  __device__ void operator()(int r, int c, float v) const {
    if (isS) {
      Sc[(size_t)r * 4096 + c] = f2bf(v);
    } else {
      u16 h = f2bf(v);
      u16 l = f2bf(v - bf2f(h));
      size_t b = (size_t)r * 3072 + c;
      qc3[b] = h; qc3[b + 1024] = l; qc3[b + 2048] = h;
    }
  }
};

struct EpiSbf {       // CL: store bf16 (sign-preserving)
  u16* sc;
  __device__ void operator()(int r, int c, float v) const {
    sc[(size_t)r * 4096 + c] = f2bf(v);
  }
};

struct EpiOut {       // G4: boundary blend
  const float* x; const float* bm; float* out;
  __device__ void operator()(int r, int c, float v) const {
    float b = bm[r];
    out[(size_t)r * 1024 + c] = b * v + (1.0f - b) * x[(size_t)r * 1024 + c];
  }
};

template <class Epi>
__device__ __forceinline__ void gemm_core(
    const u16* __restrict__ A, const u16* __restrict__ B,
    int lda, int ldb, int K, int mBase, int nBase, Epi epi) {
  __shared__ __align__(16) u16 lA[128 * 64];
  __shared__ __align__(16) u16 lB[128 * 64];
  const int tid = threadIdx.x;
  const int wave = tid >> 6, lane = tid & 63;
  const int wm = wave & 1, wn = wave >> 1;
  const int lane16 = lane & 15, quad = lane >> 4;

  // staging: thread t stages rows (t>>3)+32i, phys slot (t&7),
  // global chunk = (t&7) ^ (row&7)   (row&7 invariant under +32)
  const int srow = tid >> 3;
  const int gchunk = ((tid & 7) ^ (srow & 7)) * 8;
  const u16* aP = A + (size_t)(mBase + srow) * lda + gchunk;
  const u16* bP = B + (size_t)(nBase + srow) * ldb + gchunk;
  const int woff = wave * 1024;   // issue i covers rows [32i,32i+32)

  const int rsw = lane16 & 7;
  const u16* raB = lA + (wm * 64 + lane16) * 64;
  const u16* rbB = lB + (wn * 64 + lane16) * 64;

  f32x4 acc[4][4];
#pragma unroll
  for (int i = 0; i < 4; i++)
#pragma unroll
    for (int j = 0; j < 4; j++) acc[i][j] = (f32x4){0.f, 0.f, 0.f, 0.f};

  for (int k0 = 0; k0 < K; k0 += 64) {
#pragma unroll
    for (int i = 0; i < 4; i++) {
      gld16((char*)lA + i * 4096 + woff, aP + (size_t)(32 * i) * lda + k0);
      gld16((char*)lB + i * 4096 + woff, bP + (size_t)(32 * i) * ldb + k0);
    }
    __syncthreads();
    short8 af[2][4], bfr[2][4];
#pragma unroll
    for (int s = 0; s < 2; s++) {
      const int sl = (((s << 2) + quad) ^ rsw) * 8;
#pragma unroll
      for (int j = 0; j < 4; j++) {
        af[s][j]  = *(const short8*)(raB + j * 1024 + sl);
        bfr[s][j] = *(const short8*)(rbB + j * 1024 + sl);
      }
    }
#pragma unroll
    for (int s = 0; s < 2; s++)
#pragma unroll
      for (int im = 0; im < 4; im++)
#pragma unroll
        for (int in = 0; in < 4; in++)
          acc[im][in] = __builtin_amdgcn_mfma_f32_16x16x32_bf16(
              af[s][im], bfr[s][in], acc[im][in], 0, 0, 0);
    __syncthreads();
  }

#pragma unroll
  for (int im = 0; im < 4; im++)
#pragma unroll
    for (int in = 0; in < 4; in++)
#pragma unroll
      for (int i = 0; i < 4; i++) {
        int r = mBase + wm * 64 + im * 16 + quad * 4 + i;
        int c = nBase + wn * 64 + in * 16 + lane16;
        epi(r, c, acc[im][in][i]);
      }
}

template <class Epi>
__global__ __launch_bounds__(256, 2) void gemm_nt(
    const u16* __restrict__ A, const u16* __restrict__ B,
    int lda, int ldb, int K, Epi epi) {
  gemm_core(A, B, lda, ldb, K, blockIdx.y * 128, blockIdx.x * 128, epi);
}

// merged G2 (blocks x<8: qc = qs3@C3^T, K=3072) and S (x>=8: q_hi@k_hi^T, K=1024)
__global__ __launch_bounds__(256, 2) void gemm_qc_s(
    const u16* __restrict__ qs3, const u16* __restrict__ C3,
    const u16* __restrict__ k3, u16* __restrict__ qc3, u16* __restrict__ Sc) {
  const int isS = blockIdx.x >= 8;
  const u16* B = isS ? k3 : C3;
  const int nBase = (isS ? blockIdx.x - 8 : blockIdx.x) * 128;
  const int K = isS ? 1024 : 3072;
  gemm_core(qs3, B, 3072, 3072, K, blockIdx.y * 128, nBase,
            EpiQCS{qc3, Sc, isS});
}

// ---------------- mask + softmax ----------------
__global__ __launch_bounds__(256) void mask_softmax(
    const u16* __restrict__ Sc, const float* __restrict__ am,
    const float* __restrict__ lm, const float* __restrict__ bias,
    u16* __restrict__ P) {
  const int n = blockIdx.x, tid = threadIdx.x;
  const int lane = tid & 63, wave = tid >> 6;
  const float b0 = bias[0];
  const u16* Srow = Sc + (size_t)n * 4096;
  const u16* Crow = Sc + (size_t)(4096 + n) * 4096;
  const float* Arow = am + (size_t)n * 4096;
  const float* Lrow = lm + (size_t)n * 4096;

  float lg[16];
  float mx = -3.4e38f;
#pragma unroll
  for (int j = 0; j < 2; j++) {
    int base = (tid + 256 * j) * 8;
    u16x8 s8 = *(const u16x8*)(Srow + base);
    u16x8 c8 = *(const u16x8*)(Crow + base);
    f4v a0 = *(const f4v*)(Arow + base), a1 = *(const f4v*)(Arow + base + 4);
    f4v l0 = *(const f4v*)(Lrow + base), l1 = *(const f4v*)(Lrow + base + 4);
#pragma unroll
    for (int e = 0; e < 8; e++) {
      float st = (bf2f(c8[e]) + b0 > 0.f) ? 1.f : 0.f;
      float a = (e < 4) ? a0[e] : a1[e - 4];
      float l = (e < 4) ? l0[e] : l1[e - 4];
      float mv = a + st * l;
      float v = bf2f(s8[e]) * 0.03125f - 10000.f * (1.f - mv);
      lg[j * 8 + e] = v;
      mx = fmaxf(mx, v);
    }
  }
#pragma unroll
  for (int o = 32; o; o >>= 1) mx = fmaxf(mx, __shfl_xor(mx, o));
  __shared__ float smax[4], ssum[4];
  if (lane == 0) smax[wave] = mx;
  __syncthreads();
  mx = fmaxf(fmaxf(smax[0], smax[1]), fmaxf(smax[2], smax[3]));

  float sum = 0.f;
#pragma unroll
  for (int i = 0; i < 16; i++) { lg[i] = __expf(lg[i] - mx); sum += lg[i]; }
#pragma unroll
  for (int o = 32; o; o >>= 1) sum += __shfl_xor(sum, o);
  if (lane == 0) ssum[wave] = sum;
  __syncthreads();
  float inv = 1.f / (ssum[0] + ssum[1] + ssum[2] + ssum[3]);

  u16* Pr = P + (size_t)n * 4096;
#pragma unroll
  for (int j = 0; j < 2; j++) {
    int base = (tid + 256 * j) * 8;
    u16x8 o8;
#pragma unroll
    for (int e = 0; e < 8; e++) o8[e] = f2bf(lg[j * 8 + e] * inv);
    *(u16x8*)(Pr + base) = o8;
  }
}

// ---------------- launch ----------------

extern "C" void kernel_launch(void* const* d_in, const int* in_sizes, int n_in,
                              void* d_out, int out_size, void* d_ws, size_t ws_size,
                              hipStream_t stream) {
  const float* x    = (const float*)d_in[0];
  const float* am   = (const float*)d_in[1];
  const float* lm   = (const float*)d_in[2];
  const float* bm   = (const float*)d_in[3];
  const float* Wq   = (const float*)d_in[4];
  const float* bq   = (const float*)d_in[5];
  const float* Wk   = (const float*)d_in[6];
  const float* bk   = (const float*)d_in[7];
  const float* Wv   = (const float*)d_in[8];
  const float* bv   = (const float*)d_in[9];
  const float* Cc   = (const float*)d_in[10];
  const float* bias = (const float*)d_in[11];
  float* out = (float*)d_out;
  char* ws = (char*)d_ws;

  if (ws_size < 0xC010000) return;  // ~201 MB scratch

  u16*  xs3 = (u16*) (ws + 0x0000000);  // 24 MB [x_hi|x_lo|x_hi]
  u16*  W3  = (u16*) (ws + 0x1800000);  // 18 MB [W_hi|W_hi|W_lo]
  u16*  C3  = (u16*) (ws + 0x2A00000);  //  6 MB [Ct_hi|Ct_hi|Ct_lo]
  float* bp = (float*)(ws + 0x3000000); // 12 KB
  u16*  qs3 = (u16*) (ws + 0x3010000);  // 24 MB [q_hi|q_lo|q_hi]
  u16*  qc3 = (u16*) (ws + 0x4810000);  // 24 MB [qc_hi|qc_lo|qc_hi]
  u16*  k3  = (u16*) (ws + 0x6010000);  // 24 MB [k_hi|k_hi|k_lo]
  u16*  vt  = (u16*) (ws + 0x7810000);  //  8 MB v^T [1024,4096]
  u16*  Sc  = (u16*) (ws + 0x8010000);  // 64 MB bf16 [S ; cl]
  u16*  P   = (u16*) (ws + 0x0000000);  // 32 MB overlay (xs3/W3 dead by softmax)

  prep_x   <<<4096, 256, 0, stream>>>(x, xs3);
  prep_w   <<<3072, 256, 0, stream>>>(Wq, Wk, Wv, W3);
  prep_bias<<<12,   256, 0, stream>>>(bq, bk, bv, bp);
  prep_c   <<<dim3(32, 32), 256, 0, stream>>>(Cc, C3);

  // G1: qkv = xs3 @ W3^T   (M=4096, N=3072, K=3072)
  gemm_nt<<<dim3(24, 32), 256, 0, stream>>>(xs3, W3, 3072, 3072, 3072,
                                            EpiQKV{bp, qs3, k3, vt});
  // merged: qc = qs3 @ C3^T (K=3072, blocks x<8)  |  S = q_hi @ k_hi^T (K=1024)
  gemm_qc_s<<<dim3(40, 32), 256, 0, stream>>>(qs3, C3, k3, qc3, Sc);
  // CL = qc3 @ k3^T        (M=4096, N=4096, K=3072) -> Sc rows 4096..8191
  gemm_nt<<<dim3(32, 32), 256, 0, stream>>>(qc3, k3, 3072, 3072, 3072,
                                            EpiSbf{Sc + (size_t)4096 * 4096});
  // mask + softmax -> P (bf16)
  mask_softmax<<<4096, 256, 0, stream>>>(Sc, am, lm, bias, P);
  // G4: out = P @ vt^T  (M=4096, N=1024, K=4096) + boundary blend
  gemm_nt<<<dim3(8, 32), 256, 0, stream>>>(P, vt, 4096, 4096, 4096,
                                           EpiOut{x, bm, out});
}

// Round 5
// 551.904 us; speedup vs baseline: 1.3188x; 1.0636x over previous
//
#include <hip/hip_runtime.h>
#include <cstdint>

// ---------------------------------------------------------------------------
// Attention_75093208203309 on gfx950 — round 5.
// vs R4: (1) G4 (out = P@v^T) was 121 us at 284 TF — 256 blocks = 1 block/CU,
// fully latency-bound (Occupancy 10.7%). Now split-K: grid (8,32,4), each z
// does K=1024, epilogue atomicAdd into out pre-initialized with (1-bm)*x.
// (2) v columns in G1 computed with K=1024 (hi-only) — v is stored bf16, the
// 3-term split bought nothing there (saves 17 GF).
// Pipeline: prep + init_out -> G1 qkv -> [G2|S] -> CL -> softmax -> G4 atomic.
// ---------------------------------------------------------------------------

typedef __attribute__((ext_vector_type(8))) short short8;
typedef __attribute__((ext_vector_type(4))) float f32x4;
typedef __attribute__((ext_vector_type(4))) float f4v;
typedef __attribute__((ext_vector_type(4))) unsigned short u16x4;
typedef __attribute__((ext_vector_type(8))) unsigned short u16x8;

typedef unsigned short u16;

__device__ __forceinline__ u16 f2bf(float f) {
  unsigned u = __float_as_uint(f);
  u += 0x7fffu + ((u >> 16) & 1u);   // RNE
  return (u16)(u >> 16);
}
__device__ __forceinline__ float bf2f(u16 h) {
  return __uint_as_float(((unsigned)h) << 16);
}

__device__ __forceinline__ void gld16(void* lds, const void* g) {
  __builtin_amdgcn_global_load_lds(
      (__attribute__((address_space(1))) void*)g,
      (__attribute__((address_space(3))) void*)lds,
      16, 0, 0);
}

// ---------------- prep kernels ----------------

// x [4096,1024] f32 -> xs3 [4096,3072] bf16 = [hi | lo | hi]   (A-side)
__global__ void prep_x(const float* __restrict__ x, u16* __restrict__ xs3) {
  int id = blockIdx.x * 256 + threadIdx.x;       // float4 index
  int flat = id * 4;
  int n = flat >> 10, i = flat & 1023;
  f4v v = *(const f4v*)(x + (size_t)flat);
  u16x4 hi, lo;
#pragma unroll
  for (int e = 0; e < 4; e++) {
    float f = v[e];
    u16 h = f2bf(f);
    hi[e] = h;
    lo[e] = f2bf(f - bf2f(h));
  }
  size_t base = (size_t)n * 3072 + i;
  *(u16x4*)(xs3 + base) = hi;
  *(u16x4*)(xs3 + base + 1024) = lo;
  *(u16x4*)(xs3 + base + 2048) = hi;
}

// W_{q,k,v} [1024,1024] -> W3 [3072 rows, 3072] bf16 = [hi | hi | lo]  (B-side)
__global__ void prep_w(const float* __restrict__ Wq, const float* __restrict__ Wk,
                       const float* __restrict__ Wv, u16* __restrict__ W3) {
  int id = blockIdx.x * 256 + threadIdx.x;
  int flat = id * 4;
  int o = flat >> 10, i = flat & 1023;
  const float* src = (o < 1024) ? (Wq + (size_t)o * 1024)
                   : (o < 2048) ? (Wk + (size_t)(o - 1024) * 1024)
                                : (Wv + (size_t)(o - 2048) * 1024);
  f4v v = *(const f4v*)(src + i);
  u16x4 hi, lo;
#pragma unroll
  for (int e = 0; e < 4; e++) {
    u16 h = f2bf(v[e]);
    hi[e] = h;
    lo[e] = f2bf(v[e] - bf2f(h));
  }
  size_t base = (size_t)o * 3072 + i;
  *(u16x4*)(W3 + base) = hi;
  *(u16x4*)(W3 + base + 1024) = hi;
  *(u16x4*)(W3 + base + 2048) = lo;
}

__global__ void prep_bias(const float* __restrict__ bq, const float* __restrict__ bk,
                          const float* __restrict__ bv, float* __restrict__ bp) {
  int id = blockIdx.x * 256 + threadIdx.x;
  float v = (id < 1024) ? bq[id] : (id < 2048) ? bk[id - 1024] : bv[id - 2048];
  bp[id] = v;
}

// connection C [1024,1024] -> C3 [1024,3072]: C3[j] = [Ct_hi | Ct_hi | Ct_lo]
__global__ void prep_c(const float* __restrict__ C, u16* __restrict__ C3) {
  __shared__ float t[32][33];
  int lx = threadIdx.x & 31, ly = threadIdx.x >> 5;   // 32 x 8
  int i0 = blockIdx.x * 32, j0 = blockIdx.y * 32;
#pragma unroll
  for (int r = 0; r < 32; r += 8)
    t[ly + r][lx] = C[(size_t)(i0 + ly + r) * 1024 + j0 + lx];
  __syncthreads();
#pragma unroll
  for (int r = 0; r < 32; r += 8) {
    float f = t[lx][ly + r];                           // = C[i0+lx][j0+ly+r]
    u16 h = f2bf(f);
    u16 l = f2bf(f - bf2f(h));
    size_t o = (size_t)(j0 + ly + r) * 3072 + i0 + lx;
    C3[o] = h;
    C3[o + 1024] = h;
    C3[o + 2048] = l;
  }
}

// out = (1 - bm) * x   (G4 atomics add bm * (attention@v) on top)
__global__ void init_out(const float* __restrict__ x, const float* __restrict__ bm,
                         float* __restrict__ out) {
  int id = blockIdx.x * 256 + threadIdx.x;
  int flat = id * 4;
  int r = flat >> 10;
  float b = 1.0f - bm[r];
  f4v v = *(const f4v*)(x + (size_t)flat);
  f4v o;
#pragma unroll
  for (int e = 0; e < 4; e++) o[e] = b * v[e];
  *(f4v*)(out + (size_t)flat) = o;
}

// ---------------- NT GEMM core, BK=64 + XOR bank swizzle ----------------
// C[M,N] = A[M,K] @ B[N,K]^T, bf16 in, fp32 accum, 128x128 tile, 4 waves,
// 16x16x32 bf16 MFMA, global_load_lds width 16, 64-deep K-step.
// LDS: row-major [128 rows][8 slots of 8 elems], row stride 128 B (=32 banks).
// Row r's k-chunk c lives at slot c ^ (r&7); staging thread t fetches global
// chunk (t&7)^((t>>3)&7); reader uses slot ((4s+quad) ^ (lane16&7)).
// Uniform 8 dwords/bank -> 0 conflicts (verified R3->R4: counter 2.5e7 -> 0).

struct EpiQKV {       // G1: columns [0,1024)=q, [1024,2048)=k, [2048,3072)=v
  const float* bp; u16* qs3; u16* k3; u16* vt;
  __device__ void operator()(int r, int c, float v) const {
    v += bp[c];
    u16 h = f2bf(v);
    u16 l = f2bf(v - bf2f(h));
    if (c < 1024) {                       // q: A-side [hi|lo|hi]
      size_t b = (size_t)r * 3072 + c;
      qs3[b] = h; qs3[b + 1024] = l; qs3[b + 2048] = h;
    } else if (c < 2048) {                // k: B-side [hi|hi|lo]
      size_t b = (size_t)r * 3072 + (c - 1024);
      k3[b] = h; k3[b + 1024] = h; k3[b + 2048] = l;
    } else {                              // v: transposed, single bf16
      vt[(size_t)(c - 2048) * 4096 + r] = h;
    }
  }
};

struct EpiQCS {       // merged G2/S epilogue
  u16* qc3; u16* Sc; int isS;
  __device__ void operator()(int r, int c, float v) const {
    if (isS) {
      Sc[(size_t)r * 4096 + c] = f2bf(v);
    } else {
      u16 h = f2bf(v);
      u16 l = f2bf(v - bf2f(h));
      size_t b = (size_t)r * 3072 + c;
      qc3[b] = h; qc3[b + 1024] = l; qc3[b + 2048] = h;
    }
  }
};

struct EpiSbf {       // CL: store bf16 (sign-preserving)
  u16* sc;
  __device__ void operator()(int r, int c, float v) const {
    sc[(size_t)r * 4096 + c] = f2bf(v);
  }
};

struct EpiPV {        // G4 split-K: atomic accumulate bm-scaled partial
  const float* bm; float* out;
  __device__ void operator()(int r, int c, float v) const {
    atomicAdd(out + (size_t)r * 1024 + c, bm[r] * v);
  }
};

template <class Epi>
__device__ __forceinline__ void gemm_core(
    const u16* __restrict__ A, const u16* __restrict__ B,
    int lda, int ldb, int K, int mBase, int nBase, Epi epi) {
  __shared__ __align__(16) u16 lA[128 * 64];
  __shared__ __align__(16) u16 lB[128 * 64];
  const int tid = threadIdx.x;
  const int wave = tid >> 6, lane = tid & 63;
  const int wm = wave & 1, wn = wave >> 1;
  const int lane16 = lane & 15, quad = lane >> 4;

  // staging: thread t stages rows (t>>3)+32i, phys slot (t&7),
  // global chunk = (t&7) ^ (row&7)   (row&7 invariant under +32)
  const int srow = tid >> 3;
  const int gchunk = ((tid & 7) ^ (srow & 7)) * 8;
  const u16* aP = A + (size_t)(mBase + srow) * lda + gchunk;
  const u16* bP = B + (size_t)(nBase + srow) * ldb + gchunk;
  const int woff = wave * 1024;   // issue i covers rows [32i,32i+32)

  const int rsw = lane16 & 7;
  const u16* raB = lA + (wm * 64 + lane16) * 64;
  const u16* rbB = lB + (wn * 64 + lane16) * 64;

  f32x4 acc[4][4];
#pragma unroll
  for (int i = 0; i < 4; i++)
#pragma unroll
    for (int j = 0; j < 4; j++) acc[i][j] = (f32x4){0.f, 0.f, 0.f, 0.f};

  for (int k0 = 0; k0 < K; k0 += 64) {
#pragma unroll
    for (int i = 0; i < 4; i++) {
      gld16((char*)lA + i * 4096 + woff, aP + (size_t)(32 * i) * lda + k0);
      gld16((char*)lB + i * 4096 + woff, bP + (size_t)(32 * i) * ldb + k0);
    }
    __syncthreads();
    short8 af[2][4], bfr[2][4];
#pragma unroll
    for (int s = 0; s < 2; s++) {
      const int sl = (((s << 2) + quad) ^ rsw) * 8;
#pragma unroll
      for (int j = 0; j < 4; j++) {
        af[s][j]  = *(const short8*)(raB + j * 1024 + sl);
        bfr[s][j] = *(const short8*)(rbB + j * 1024 + sl);
      }
    }
#pragma unroll
    for (int s = 0; s < 2; s++)
#pragma unroll
      for (int im = 0; im < 4; im++)
#pragma unroll
        for (int in = 0; in < 4; in++)
          acc[im][in] = __builtin_amdgcn_mfma_f32_16x16x32_bf16(
              af[s][im], bfr[s][in], acc[im][in], 0, 0, 0);
    __syncthreads();
  }

#pragma unroll
  for (int im = 0; im < 4; im++)
#pragma unroll
    for (int in = 0; in < 4; in++)
#pragma unroll
      for (int i = 0; i < 4; i++) {
        int r = mBase + wm * 64 + im * 16 + quad * 4 + i;
        int c = nBase + wn * 64 + in * 16 + lane16;
        epi(r, c, acc[im][in][i]);
      }
}

template <class Epi>
__global__ __launch_bounds__(256, 2) void gemm_nt(
    const u16* __restrict__ A, const u16* __restrict__ B,
    int lda, int ldb, int K, Epi epi) {
  gemm_core(A, B, lda, ldb, K, blockIdx.y * 128, blockIdx.x * 128, epi);
}

// G1 with per-block K: v columns (x>=16) only need hi*hi (K=1024)
__global__ __launch_bounds__(256, 2) void gemm_qkv(
    const u16* __restrict__ xs3, const u16* __restrict__ W3, EpiQKV epi) {
  const int K = (blockIdx.x >= 16) ? 1024 : 3072;
  gemm_core(xs3, W3, 3072, 3072, K, blockIdx.y * 128, blockIdx.x * 128, epi);
}

// merged G2 (x<8: qc = qs3@C3^T, K=3072) and S (x>=8: q_hi@k_hi^T, K=1024)
__global__ __launch_bounds__(256, 2) void gemm_qc_s(
    const u16* __restrict__ qs3, const u16* __restrict__ C3,
    const u16* __restrict__ k3, u16* __restrict__ qc3, u16* __restrict__ Sc) {
  const int isS = blockIdx.x >= 8;
  const u16* B = isS ? k3 : C3;
  const int nBase = (isS ? blockIdx.x - 8 : blockIdx.x) * 128;
  const int K = isS ? 1024 : 3072;
  gemm_core(qs3, B, 3072, 3072, K, blockIdx.y * 128, nBase,
            EpiQCS{qc3, Sc, isS});
}

// G4 split-K: z-th slice does K in [1024z, 1024z+1024), atomics into out
__global__ __launch_bounds__(256, 2) void gemm_pv(
    const u16* __restrict__ P, const u16* __restrict__ vt,
    const float* __restrict__ bm, float* __restrict__ out) {
  const size_t kOff = (size_t)blockIdx.z * 1024;
  gemm_core(P + kOff, vt + kOff, 4096, 4096, 1024,
            blockIdx.y * 128, blockIdx.x * 128, EpiPV{bm, out});
}

// ---------------- mask + softmax ----------------
__global__ __launch_bounds__(256) void mask_softmax(
    const u16* __restrict__ Sc, const float* __restrict__ am,
    const float* __restrict__ lm, const float* __restrict__ bias,
    u16* __restrict__ P) {
  const int n = blockIdx.x, tid = threadIdx.x;
  const int lane = tid & 63, wave = tid >> 6;
  const float b0 = bias[0];
  const u16* Srow = Sc + (size_t)n * 4096;
  const u16* Crow = Sc + (size_t)(4096 + n) * 4096;
  const float* Arow = am + (size_t)n * 4096;
  const float* Lrow = lm + (size_t)n * 4096;

  float lg[16];
  float mx = -3.4e38f;
#pragma unroll
  for (int j = 0; j < 2; j++) {
    int base = (tid + 256 * j) * 8;
    u16x8 s8 = *(const u16x8*)(Srow + base);
    u16x8 c8 = *(const u16x8*)(Crow + base);
    f4v a0 = *(const f4v*)(Arow + base), a1 = *(const f4v*)(Arow + base + 4);
    f4v l0 = *(const f4v*)(Lrow + base), l1 = *(const f4v*)(Lrow + base + 4);
#pragma unroll
    for (int e = 0; e < 8; e++) {
      float st = (bf2f(c8[e]) + b0 > 0.f) ? 1.f : 0.f;
      float a = (e < 4) ? a0[e] : a1[e - 4];
      float l = (e < 4) ? l0[e] : l1[e - 4];
      float mv = a + st * l;
      float v = bf2f(s8[e]) * 0.03125f - 10000.f * (1.f - mv);
      lg[j * 8 + e] = v;
      mx = fmaxf(mx, v);
    }
  }
#pragma unroll
  for (int o = 32; o; o >>= 1) mx = fmaxf(mx, __shfl_xor(mx, o));
  __shared__ float smax[4], ssum[4];
  if (lane == 0) smax[wave] = mx;
  __syncthreads();
  mx = fmaxf(fmaxf(smax[0], smax[1]), fmaxf(smax[2], smax[3]));

  float sum = 0.f;
#pragma unroll
  for (int i = 0; i < 16; i++) { lg[i] = __expf(lg[i] - mx); sum += lg[i]; }
#pragma unroll
  for (int o = 32; o; o >>= 1) sum += __shfl_xor(sum, o);
  if (lane == 0) ssum[wave] = sum;
  __syncthreads();
  float inv = 1.f / (ssum[0] + ssum[1] + ssum[2] + ssum[3]);

  u16* Pr = P + (size_t)n * 4096;
#pragma unroll
  for (int j = 0; j < 2; j++) {
    int base = (tid + 256 * j) * 8;
    u16x8 o8;
#pragma unroll
    for (int e = 0; e < 8; e++) o8[e] = f2bf(lg[j * 8 + e] * inv);
    *(u16x8*)(Pr + base) = o8;
  }
}

// ---------------- launch ----------------

extern "C" void kernel_launch(void* const* d_in, const int* in_sizes, int n_in,
                              void* d_out, int out_size, void* d_ws, size_t ws_size,
                              hipStream_t stream) {
  const float* x    = (const float*)d_in[0];
  const float* am   = (const float*)d_in[1];
  const float* lm   = (const float*)d_in[2];
  const float* bm   = (const float*)d_in[3];
  const float* Wq   = (const float*)d_in[4];
  const float* bq   = (const float*)d_in[5];
  const float* Wk   = (const float*)d_in[6];
  const float* bk   = (const float*)d_in[7];
  const float* Wv   = (const float*)d_in[8];
  const float* bv   = (const float*)d_in[9];
  const float* Cc   = (const float*)d_in[10];
  const float* bias = (const float*)d_in[11];
  float* out = (float*)d_out;
  char* ws = (char*)d_ws;

  if (ws_size < 0xC010000) return;  // ~201 MB scratch

  u16*  xs3 = (u16*) (ws + 0x0000000);  // 24 MB [x_hi|x_lo|x_hi]
  u16*  W3  = (u16*) (ws + 0x1800000);  // 18 MB [W_hi|W_hi|W_lo]
  u16*  C3  = (u16*) (ws + 0x2A00000);  //  6 MB [Ct_hi|Ct_hi|Ct_lo]
  float* bp = (float*)(ws + 0x3000000); // 12 KB
  u16*  qs3 = (u16*) (ws + 0x3010000);  // 24 MB [q_hi|q_lo|q_hi]
  u16*  qc3 = (u16*) (ws + 0x4810000);  // 24 MB [qc_hi|qc_lo|qc_hi]
  u16*  k3  = (u16*) (ws + 0x6010000);  // 24 MB [k_hi|k_hi|k_lo]
  u16*  vt  = (u16*) (ws + 0x7810000);  //  8 MB v^T [1024,4096]
  u16*  Sc  = (u16*) (ws + 0x8010000);  // 64 MB bf16 [S ; cl]
  u16*  P   = (u16*) (ws + 0x0000000);  // 32 MB overlay (xs3/W3 dead by softmax)

  prep_x   <<<4096, 256, 0, stream>>>(x, xs3);
  prep_w   <<<3072, 256, 0, stream>>>(Wq, Wk, Wv, W3);
  prep_bias<<<12,   256, 0, stream>>>(bq, bk, bv, bp);
  prep_c   <<<dim3(32, 32), 256, 0, stream>>>(Cc, C3);
  init_out <<<4096, 256, 0, stream>>>(x, bm, out);

  // G1: qkv = xs3 @ W3^T   (M=4096, N=3072; K=3072 for q/k, 1024 for v)
  gemm_qkv<<<dim3(24, 32), 256, 0, stream>>>(xs3, W3, EpiQKV{bp, qs3, k3, vt});
  // merged: qc = qs3 @ C3^T (K=3072, x<8)  |  S = q_hi @ k_hi^T (K=1024)
  gemm_qc_s<<<dim3(40, 32), 256, 0, stream>>>(qs3, C3, k3, qc3, Sc);
  // CL = qc3 @ k3^T        (M=4096, N=4096, K=3072) -> Sc rows 4096..8191
  gemm_nt<<<dim3(32, 32), 256, 0, stream>>>(qc3, k3, 3072, 3072, 3072,
                                            EpiSbf{Sc + (size_t)4096 * 4096});
  // mask + softmax -> P (bf16)
  mask_softmax<<<4096, 256, 0, stream>>>(Sc, am, lm, bias, P);
  // G4: out += bm * (P @ vt^T), split-K over 4 z-slices (atomics)
  gemm_pv<<<dim3(8, 32, 4), 256, 0, stream>>>(P, vt, bm, out);
}

// Round 6
// 521.293 us; speedup vs baseline: 1.3963x; 1.0587x over previous
//
#include <hip/hip_runtime.h>
#include <cstdint>

// ---------------------------------------------------------------------------
// Attention_75093208203309 on gfx950 — round 6.
// vs R5: (1) v^T computed as NT-GEMM (Wv@x^T, coalesced stores) inside the G1
// dispatch — removes 4.1M scattered 2B stores (cache-line RMW). (2) G4 uses
// split-K=2 with plain fp32 partial stores + reduce_out (67M atomicAdds and
// init_out eliminated). (3) CL epilogue emits st = sign(cl+bias) as u8 from
// the fp32 accumulator (-48 MB traffic, one less rounding); softmax reads u8.
// Pipeline: preps -> G1(q,k,vt) -> [qc|S] -> CL->st -> softmax -> G4 -> reduce.
// ---------------------------------------------------------------------------

typedef __attribute__((ext_vector_type(8))) short short8;
typedef __attribute__((ext_vector_type(4))) float f32x4;
typedef __attribute__((ext_vector_type(4))) float f4v;
typedef __attribute__((ext_vector_type(4))) unsigned short u16x4;
typedef __attribute__((ext_vector_type(8))) unsigned short u16x8;

typedef unsigned short u16;
typedef unsigned char u8;

__device__ __forceinline__ u16 f2bf(float f) {
  unsigned u = __float_as_uint(f);
  u += 0x7fffu + ((u >> 16) & 1u);   // RNE
  return (u16)(u >> 16);
}
__device__ __forceinline__ float bf2f(u16 h) {
  return __uint_as_float(((unsigned)h) << 16);
}

__device__ __forceinline__ void gld16(void* lds, const void* g) {
  __builtin_amdgcn_global_load_lds(
      (__attribute__((address_space(1))) void*)g,
      (__attribute__((address_space(3))) void*)lds,
      16, 0, 0);
}

// ---------------- prep kernels ----------------

// x [4096,1024] f32 -> xs3 [4096,3072] bf16 = [hi | lo | hi]   (A-side)
__global__ void prep_x(const float* __restrict__ x, u16* __restrict__ xs3) {
  int id = blockIdx.x * 256 + threadIdx.x;       // float4 index
  int flat = id * 4;
  int n = flat >> 10, i = flat & 1023;
  f4v v = *(const f4v*)(x + (size_t)flat);
  u16x4 hi, lo;
#pragma unroll
  for (int e = 0; e < 4; e++) {
    float f = v[e];
    u16 h = f2bf(f);
    hi[e] = h;
    lo[e] = f2bf(f - bf2f(h));
  }
  size_t base = (size_t)n * 3072 + i;
  *(u16x4*)(xs3 + base) = hi;
  *(u16x4*)(xs3 + base + 1024) = lo;
  *(u16x4*)(xs3 + base + 2048) = hi;
}

// W_{q,k,v} [1024,1024] -> W3 [3072 rows, 3072] bf16 = [hi | hi | lo]  (B-side)
__global__ void prep_w(const float* __restrict__ Wq, const float* __restrict__ Wk,
                       const float* __restrict__ Wv, u16* __restrict__ W3) {
  int id = blockIdx.x * 256 + threadIdx.x;
  int flat = id * 4;
  int o = flat >> 10, i = flat & 1023;
  const float* src = (o < 1024) ? (Wq + (size_t)o * 1024)
                   : (o < 2048) ? (Wk + (size_t)(o - 1024) * 1024)
                                : (Wv + (size_t)(o - 2048) * 1024);
  f4v v = *(const f4v*)(src + i);
  u16x4 hi, lo;
#pragma unroll
  for (int e = 0; e < 4; e++) {
    u16 h = f2bf(v[e]);
    hi[e] = h;
    lo[e] = f2bf(v[e] - bf2f(h));
  }
  size_t base = (size_t)o * 3072 + i;
  *(u16x4*)(W3 + base) = hi;
  *(u16x4*)(W3 + base + 1024) = hi;
  *(u16x4*)(W3 + base + 2048) = lo;
}

__global__ void prep_bias(const float* __restrict__ bq, const float* __restrict__ bk,
                          const float* __restrict__ bv, float* __restrict__ bp) {
  int id = blockIdx.x * 256 + threadIdx.x;
  float v = (id < 1024) ? bq[id] : (id < 2048) ? bk[id - 1024] : bv[id - 2048];
  bp[id] = v;
}

// connection C [1024,1024] -> C3 [1024,3072]: C3[j] = [Ct_hi | Ct_hi | Ct_lo]
__global__ void prep_c(const float* __restrict__ C, u16* __restrict__ C3) {
  __shared__ float t[32][33];
  int lx = threadIdx.x & 31, ly = threadIdx.x >> 5;   // 32 x 8
  int i0 = blockIdx.x * 32, j0 = blockIdx.y * 32;
#pragma unroll
  for (int r = 0; r < 32; r += 8)
    t[ly + r][lx] = C[(size_t)(i0 + ly + r) * 1024 + j0 + lx];
  __syncthreads();
#pragma unroll
  for (int r = 0; r < 32; r += 8) {
    float f = t[lx][ly + r];                           // = C[i0+lx][j0+ly+r]
    u16 h = f2bf(f);
    u16 l = f2bf(f - bf2f(h));
    size_t o = (size_t)(j0 + ly + r) * 3072 + i0 + lx;
    C3[o] = h;
    C3[o + 1024] = h;
    C3[o + 2048] = l;
  }
}

// ---------------- NT GEMM core, BK=64 + XOR bank swizzle ----------------
// C[M,N] = A[M,K] @ B[N,K]^T, bf16 in, fp32 accum, 128x128 tile, 4 waves,
// 16x16x32 bf16 MFMA, global_load_lds width 16, 64-deep K-step.
// LDS: row-major [128 rows][8 slots of 8 elems], row stride 128 B (=32 banks).
// Row r's k-chunk c lives at slot c ^ (r&7); staging thread t fetches global
// chunk (t&7)^((t>>3)&7); reader uses slot ((4s+quad) ^ (lane16&7)).
// Uniform 8 dwords/bank -> 0 conflicts (verified: counter 2.5e7 -> 0).

struct EpiG1 {        // mode 0: q/k columns; mode 1: vt = Wv@x^T + bv
  const float* bp; u16* qs3; u16* k3; u16* vt; int mode;
  __device__ void operator()(int r, int c, float v) const {
    if (mode == 0) {
      v += bp[c];
      u16 h = f2bf(v);
      u16 l = f2bf(v - bf2f(h));
      if (c < 1024) {                     // q: A-side [hi|lo|hi]
        size_t b = (size_t)r * 3072 + c;
        qs3[b] = h; qs3[b + 1024] = l; qs3[b + 2048] = h;
      } else {                            // k: B-side [hi|hi|lo]
        size_t b = (size_t)r * 3072 + (c - 1024);
        k3[b] = h; k3[b + 1024] = h; k3[b + 2048] = l;
      }
    } else {                              // vt[r][c], r = Wv row, c = x row
      v += bp[2048 + r];
      vt[(size_t)r * 4096 + c] = f2bf(v); // coalesced in c (lane16)
    }
  }
};

struct EpiQCS {       // merged G2/S epilogue
  u16* qc3; u16* Sc; int isS;
  __device__ void operator()(int r, int c, float v) const {
    if (isS) {
      Sc[(size_t)r * 4096 + c] = f2bf(v);
    } else {
      u16 h = f2bf(v);
      u16 l = f2bf(v - bf2f(h));
      size_t b = (size_t)r * 3072 + c;
      qc3[b] = h; qc3[b + 1024] = l; qc3[b + 2048] = h;
    }
  }
};

struct EpiCL {        // CL: straight-through mask bit from fp32 accumulator
  u8* st; float b0;
  __device__ void operator()(int r, int c, float v) const {
    st[(size_t)r * 4096 + c] = (v + b0 > 0.f) ? 1 : 0;
  }
};

struct EpiPart {      // G4 split-K: plain partial store
  float* part;
  __device__ void operator()(int r, int c, float v) const {
    part[(size_t)r * 1024 + c] = v;
  }
};

template <class Epi>
__device__ __forceinline__ void gemm_core(
    const u16* __restrict__ A, const u16* __restrict__ B,
    int lda, int ldb, int K, int mBase, int nBase, Epi epi) {
  __shared__ __align__(16) u16 lA[128 * 64];
  __shared__ __align__(16) u16 lB[128 * 64];
  const int tid = threadIdx.x;
  const int wave = tid >> 6, lane = tid & 63;
  const int wm = wave & 1, wn = wave >> 1;
  const int lane16 = lane & 15, quad = lane >> 4;

  // staging: thread t stages rows (t>>3)+32i, phys slot (t&7),
  // global chunk = (t&7) ^ (row&7)   (row&7 invariant under +32)
  const int srow = tid >> 3;
  const int gchunk = ((tid & 7) ^ (srow & 7)) * 8;
  const u16* aP = A + (size_t)(mBase + srow) * lda + gchunk;
  const u16* bP = B + (size_t)(nBase + srow) * ldb + gchunk;
  const int woff = wave * 1024;   // issue i covers rows [32i,32i+32)

  const int rsw = lane16 & 7;
  const u16* raB = lA + (wm * 64 + lane16) * 64;
  const u16* rbB = lB + (wn * 64 + lane16) * 64;

  f32x4 acc[4][4];
#pragma unroll
  for (int i = 0; i < 4; i++)
#pragma unroll
    for (int j = 0; j < 4; j++) acc[i][j] = (f32x4){0.f, 0.f, 0.f, 0.f};

  for (int k0 = 0; k0 < K; k0 += 64) {
#pragma unroll
    for (int i = 0; i < 4; i++) {
      gld16((char*)lA + i * 4096 + woff, aP + (size_t)(32 * i) * lda + k0);
      gld16((char*)lB + i * 4096 + woff, bP + (size_t)(32 * i) * ldb + k0);
    }
    __syncthreads();
    short8 af[2][4], bfr[2][4];
#pragma unroll
    for (int s = 0; s < 2; s++) {
      const int sl = (((s << 2) + quad) ^ rsw) * 8;
#pragma unroll
      for (int j = 0; j < 4; j++) {
        af[s][j]  = *(const short8*)(raB + j * 1024 + sl);
        bfr[s][j] = *(const short8*)(rbB + j * 1024 + sl);
      }
    }
#pragma unroll
    for (int s = 0; s < 2; s++)
#pragma unroll
      for (int im = 0; im < 4; im++)
#pragma unroll
        for (int in = 0; in < 4; in++)
          acc[im][in] = __builtin_amdgcn_mfma_f32_16x16x32_bf16(
              af[s][im], bfr[s][in], acc[im][in], 0, 0, 0);
    __syncthreads();
  }

#pragma unroll
  for (int im = 0; im < 4; im++)
#pragma unroll
    for (int in = 0; in < 4; in++)
#pragma unroll
      for (int i = 0; i < 4; i++) {
        int r = mBase + wm * 64 + im * 16 + quad * 4 + i;
        int c = nBase + wn * 64 + in * 16 + lane16;
        epi(r, c, acc[im][in][i]);
      }
}

// G1: x<16 -> q,k = xs3@W3^T (K=3072); x>=16 -> vt = Wv_hi@x_hi^T (K=1024)
__global__ __launch_bounds__(256, 2) void gemm_g1(
    const u16* __restrict__ xs3, const u16* __restrict__ W3,
    const float* __restrict__ bp, u16* __restrict__ qs3,
    u16* __restrict__ k3, u16* __restrict__ vt) {
  const int bx = blockIdx.x, by = blockIdx.y;
  if (bx < 16) {
    gemm_core(xs3, W3, 3072, 3072, 3072, by * 128, bx * 128,
              EpiG1{bp, qs3, k3, vt, 0});
  } else {
    gemm_core(W3 + (size_t)2048 * 3072, xs3, 3072, 3072, 1024,
              (bx - 16) * 128, by * 128, EpiG1{bp, qs3, k3, vt, 1});
  }
}

// merged G2 (x<8: qc = qs3@C3^T, K=3072) and S (x>=8: q_hi@k_hi^T, K=1024)
__global__ __launch_bounds__(256, 2) void gemm_qc_s(
    const u16* __restrict__ qs3, const u16* __restrict__ C3,
    const u16* __restrict__ k3, u16* __restrict__ qc3, u16* __restrict__ Sc) {
  const int isS = blockIdx.x >= 8;
  const u16* B = isS ? k3 : C3;
  const int nBase = (isS ? blockIdx.x - 8 : blockIdx.x) * 128;
  const int K = isS ? 1024 : 3072;
  gemm_core(qs3, B, 3072, 3072, K, blockIdx.y * 128, nBase,
            EpiQCS{qc3, Sc, isS});
}

// CL = qc3 @ k3^T (K=3072) -> st bits
__global__ __launch_bounds__(256, 2) void gemm_cl(
    const u16* __restrict__ qc3, const u16* __restrict__ k3,
    const float* __restrict__ bias, u8* __restrict__ st) {
  gemm_core(qc3, k3, 3072, 3072, 3072, blockIdx.y * 128, blockIdx.x * 128,
            EpiCL{st, bias[0]});
}

// G4 split-K=2: z-slice does K in [2048z, 2048z+2048) -> parts[z]
__global__ __launch_bounds__(256, 2) void gemm_pv(
    const u16* __restrict__ P, const u16* __restrict__ vt,
    float* __restrict__ parts) {
  const size_t kOff = (size_t)blockIdx.z * 2048;
  gemm_core(P + kOff, vt + kOff, 4096, 4096, 2048,
            blockIdx.y * 128, blockIdx.x * 128,
            EpiPart{parts + (size_t)blockIdx.z * 4096 * 1024});
}

// out = (1-bm)*x + bm*(p0 + p1)
__global__ void reduce_out(const float* __restrict__ x, const float* __restrict__ bm,
                           const float* __restrict__ parts, float* __restrict__ out) {
  int id = blockIdx.x * 256 + threadIdx.x;
  int flat = id * 4;
  int r = flat >> 10;
  float b = bm[r];
  f4v xv = *(const f4v*)(x + (size_t)flat);
  f4v p0 = *(const f4v*)(parts + (size_t)flat);
  f4v p1 = *(const f4v*)(parts + (size_t)4096 * 1024 + flat);
  f4v o;
#pragma unroll
  for (int e = 0; e < 4; e++) o[e] = b * (p0[e] + p1[e]) + (1.0f - b) * xv[e];
  *(f4v*)(out + (size_t)flat) = o;
}

// ---------------- mask + softmax ----------------
// logits = S/32 - 10000*(1 - am - st*lm); P = softmax(row).
__global__ __launch_bounds__(256) void mask_softmax(
    const u16* __restrict__ Sc, const u8* __restrict__ st,
    const float* __restrict__ am, const float* __restrict__ lm,
    u16* __restrict__ P) {
  const int n = blockIdx.x, tid = threadIdx.x;
  const int lane = tid & 63, wave = tid >> 6;
  const u16* Srow = Sc + (size_t)n * 4096;
  const u8* Trow = st + (size_t)n * 4096;
  const float* Arow = am + (size_t)n * 4096;
  const float* Lrow = lm + (size_t)n * 4096;

  float lg[16];
  float mx = -3.4e38f;
#pragma unroll
  for (int j = 0; j < 2; j++) {
    int base = (tid + 256 * j) * 8;
    u16x8 s8 = *(const u16x8*)(Srow + base);
    unsigned long long t8 = *(const unsigned long long*)(Trow + base);
    f4v a0 = *(const f4v*)(Arow + base), a1 = *(const f4v*)(Arow + base + 4);
    f4v l0 = *(const f4v*)(Lrow + base), l1 = *(const f4v*)(Lrow + base + 4);
#pragma unroll
    for (int e = 0; e < 8; e++) {
      float stv = ((t8 >> (8 * e)) & 1ull) ? 1.f : 0.f;
      float a = (e < 4) ? a0[e] : a1[e - 4];
      float l = (e < 4) ? l0[e] : l1[e - 4];
      float mv = a + stv * l;
      float v = bf2f(s8[e]) * 0.03125f - 10000.f * (1.f - mv);
      lg[j * 8 + e] = v;
      mx = fmaxf(mx, v);
    }
  }
#pragma unroll
  for (int o = 32; o; o >>= 1) mx = fmaxf(mx, __shfl_xor(mx, o));
  __shared__ float smax[4], ssum[4];
  if (lane == 0) smax[wave] = mx;
  __syncthreads();
  mx = fmaxf(fmaxf(smax[0], smax[1]), fmaxf(smax[2], smax[3]));

  float sum = 0.f;
#pragma unroll
  for (int i = 0; i < 16; i++) { lg[i] = __expf(lg[i] - mx); sum += lg[i]; }
#pragma unroll
  for (int o = 32; o; o >>= 1) sum += __shfl_xor(sum, o);
  if (lane == 0) ssum[wave] = sum;
  __syncthreads();
  float inv = 1.f / (ssum[0] + ssum[1] + ssum[2] + ssum[3]);

  u16* Pr = P + (size_t)n * 4096;
#pragma unroll
  for (int j = 0; j < 2; j++) {
    int base = (tid + 256 * j) * 8;
    u16x8 o8;
#pragma unroll
    for (int e = 0; e < 8; e++) o8[e] = f2bf(lg[j * 8 + e] * inv);
    *(u16x8*)(Pr + base) = o8;
  }
}

// ---------------- launch ----------------

extern "C" void kernel_launch(void* const* d_in, const int* in_sizes, int n_in,
                              void* d_out, int out_size, void* d_ws, size_t ws_size,
                              hipStream_t stream) {
  const float* x    = (const float*)d_in[0];
  const float* am   = (const float*)d_in[1];
  const float* lm   = (const float*)d_in[2];
  const float* bm   = (const float*)d_in[3];
  const float* Wq   = (const float*)d_in[4];
  const float* bq   = (const float*)d_in[5];
  const float* Wk   = (const float*)d_in[6];
  const float* bk   = (const float*)d_in[7];
  const float* Wv   = (const float*)d_in[8];
  const float* bv   = (const float*)d_in[9];
  const float* Cc   = (const float*)d_in[10];
  const float* bias = (const float*)d_in[11];
  float* out = (float*)d_out;
  char* ws = (char*)d_ws;

  if (ws_size < 0xB010000) return;  // ~176 MB scratch

  u16*  xs3 = (u16*) (ws + 0x0000000);  // 24 MB [x_hi|x_lo|x_hi]
  u16*  W3  = (u16*) (ws + 0x1800000);  // 18 MB [W_hi|W_hi|W_lo]
  u16*  C3  = (u16*) (ws + 0x2A00000);  //  6 MB [Ct_hi|Ct_hi|Ct_lo]
  float* bp = (float*)(ws + 0x3000000); // 12 KB
  u16*  qs3 = (u16*) (ws + 0x3010000);  // 24 MB [q_hi|q_lo|q_hi]
  u16*  qc3 = (u16*) (ws + 0x4810000);  // 24 MB [qc_hi|qc_lo|qc_hi]
  u16*  k3  = (u16*) (ws + 0x6010000);  // 24 MB [k_hi|k_hi|k_lo]
  u16*  vt  = (u16*) (ws + 0x7810000);  //  8 MB v^T [1024,4096]
  u16*  Sc  = (u16*) (ws + 0x8010000);  // 32 MB bf16 S
  u8*   st  = (u8*)  (ws + 0xA010000);  // 16 MB straight-through bits
  u16*  P   = (u16*) (ws + 0x0000000);  // 32 MB overlay (xs3/W3-head dead)
  float* parts = (float*)(ws + 0x4810000); // 32 MB overlay (qc3/k3-head dead)

  prep_x   <<<4096, 256, 0, stream>>>(x, xs3);
  prep_w   <<<3072, 256, 0, stream>>>(Wq, Wk, Wv, W3);
  prep_bias<<<12,   256, 0, stream>>>(bq, bk, bv, bp);
  prep_c   <<<dim3(32, 32), 256, 0, stream>>>(Cc, C3);

  // G1: q,k = xs3 @ W3^T (K=3072) | vt = Wv@x^T (K=1024), one dispatch
  gemm_g1<<<dim3(24, 32), 256, 0, stream>>>(xs3, W3, bp, qs3, k3, vt);
  // merged: qc = qs3 @ C3^T (K=3072, x<8)  |  S = q_hi @ k_hi^T (K=1024)
  gemm_qc_s<<<dim3(40, 32), 256, 0, stream>>>(qs3, C3, k3, qc3, Sc);
  // CL = qc3 @ k3^T (K=3072) -> st bits
  gemm_cl<<<dim3(32, 32), 256, 0, stream>>>(qc3, k3, bias, st);
  // mask + softmax -> P (bf16)
  mask_softmax<<<4096, 256, 0, stream>>>(Sc, st, am, lm, P);
  // G4: parts[z] = P @ vt^T over K-halves (plain stores, no atomics)
  gemm_pv<<<dim3(8, 32, 2), 256, 0, stream>>>(P, vt, parts);
  // out = (1-bm)x + bm*(p0+p1)
  reduce_out<<<4096, 256, 0, stream>>>(x, bm, parts, out);
}

// Round 7
// 488.668 us; speedup vs baseline: 1.4895x; 1.0668x over previous
//
#include <hip/hip_runtime.h>
#include <cstdint>

// ---------------------------------------------------------------------------
// Attention_75093208203309 on gfx950 — round 7.
// vs R6: long-work-first block ordering. gemm_qc_s ran at MfmaUtil 25% because
// its K=3072 qc blocks (48 iters) sat at x<8 of a (40,32) grid — HW dispatch
// is x-fastest, so the last long block entered ~97% into the launch order and
// ran its 48 iterations on an empty machine. Now 1-D grids: long blocks get
// the lowest block IDs (qc before S; qk before vt). No numeric change.
// Pipeline: preps -> G1(qk,vt) -> [qc|S] -> CL->st -> softmax -> G4 -> reduce.
// ---------------------------------------------------------------------------

typedef __attribute__((ext_vector_type(8))) short short8;
typedef __attribute__((ext_vector_type(4))) float f32x4;
typedef __attribute__((ext_vector_type(4))) float f4v;
typedef __attribute__((ext_vector_type(4))) unsigned short u16x4;
typedef __attribute__((ext_vector_type(8))) unsigned short u16x8;

typedef unsigned short u16;
typedef unsigned char u8;

__device__ __forceinline__ u16 f2bf(float f) {
  unsigned u = __float_as_uint(f);
  u += 0x7fffu + ((u >> 16) & 1u);   // RNE
  return (u16)(u >> 16);
}
__device__ __forceinline__ float bf2f(u16 h) {
  return __uint_as_float(((unsigned)h) << 16);
}

__device__ __forceinline__ void gld16(void* lds, const void* g) {
  __builtin_amdgcn_global_load_lds(
      (__attribute__((address_space(1))) void*)g,
      (__attribute__((address_space(3))) void*)lds,
      16, 0, 0);
}

// ---------------- prep kernels ----------------

// x [4096,1024] f32 -> xs3 [4096,3072] bf16 = [hi | lo | hi]   (A-side)
__global__ void prep_x(const float* __restrict__ x, u16* __restrict__ xs3) {
  int id = blockIdx.x * 256 + threadIdx.x;       // float4 index
  int flat = id * 4;
  int n = flat >> 10, i = flat & 1023;
  f4v v = *(const f4v*)(x + (size_t)flat);
  u16x4 hi, lo;
#pragma unroll
  for (int e = 0; e < 4; e++) {
    float f = v[e];
    u16 h = f2bf(f);
    hi[e] = h;
    lo[e] = f2bf(f - bf2f(h));
  }
  size_t base = (size_t)n * 3072 + i;
  *(u16x4*)(xs3 + base) = hi;
  *(u16x4*)(xs3 + base + 1024) = lo;
  *(u16x4*)(xs3 + base + 2048) = hi;
}

// W_{q,k,v} [1024,1024] -> W3 [3072 rows, 3072] bf16 = [hi | hi | lo]  (B-side)
__global__ void prep_w(const float* __restrict__ Wq, const float* __restrict__ Wk,
                       const float* __restrict__ Wv, u16* __restrict__ W3) {
  int id = blockIdx.x * 256 + threadIdx.x;
  int flat = id * 4;
  int o = flat >> 10, i = flat & 1023;
  const float* src = (o < 1024) ? (Wq + (size_t)o * 1024)
                   : (o < 2048) ? (Wk + (size_t)(o - 1024) * 1024)
                                : (Wv + (size_t)(o - 2048) * 1024);
  f4v v = *(const f4v*)(src + i);
  u16x4 hi, lo;
#pragma unroll
  for (int e = 0; e < 4; e++) {
    u16 h = f2bf(v[e]);
    hi[e] = h;
    lo[e] = f2bf(v[e] - bf2f(h));
  }
  size_t base = (size_t)o * 3072 + i;
  *(u16x4*)(W3 + base) = hi;
  *(u16x4*)(W3 + base + 1024) = hi;
  *(u16x4*)(W3 + base + 2048) = lo;
}

__global__ void prep_bias(const float* __restrict__ bq, const float* __restrict__ bk,
                          const float* __restrict__ bv, float* __restrict__ bp) {
  int id = blockIdx.x * 256 + threadIdx.x;
  float v = (id < 1024) ? bq[id] : (id < 2048) ? bk[id - 1024] : bv[id - 2048];
  bp[id] = v;
}

// connection C [1024,1024] -> C3 [1024,3072]: C3[j] = [Ct_hi | Ct_hi | Ct_lo]
__global__ void prep_c(const float* __restrict__ C, u16* __restrict__ C3) {
  __shared__ float t[32][33];
  int lx = threadIdx.x & 31, ly = threadIdx.x >> 5;   // 32 x 8
  int i0 = blockIdx.x * 32, j0 = blockIdx.y * 32;
#pragma unroll
  for (int r = 0; r < 32; r += 8)
    t[ly + r][lx] = C[(size_t)(i0 + ly + r) * 1024 + j0 + lx];
  __syncthreads();
#pragma unroll
  for (int r = 0; r < 32; r += 8) {
    float f = t[lx][ly + r];                           // = C[i0+lx][j0+ly+r]
    u16 h = f2bf(f);
    u16 l = f2bf(f - bf2f(h));
    size_t o = (size_t)(j0 + ly + r) * 3072 + i0 + lx;
    C3[o] = h;
    C3[o + 1024] = h;
    C3[o + 2048] = l;
  }
}

// ---------------- NT GEMM core, BK=64 + XOR bank swizzle ----------------
// C[M,N] = A[M,K] @ B[N,K]^T, bf16 in, fp32 accum, 128x128 tile, 4 waves,
// 16x16x32 bf16 MFMA, global_load_lds width 16, 64-deep K-step.
// LDS: row-major [128 rows][8 slots of 8 elems], row stride 128 B (=32 banks).
// Row r's k-chunk c lives at slot c ^ (r&7); staging thread t fetches global
// chunk (t&7)^((t>>3)&7); reader uses slot ((4s+quad) ^ (lane16&7)).
// Uniform 8 dwords/bank -> 0 conflicts (verified: counter 2.5e7 -> 0).

struct EpiG1 {        // mode 0: q/k columns; mode 1: vt = Wv@x^T + bv
  const float* bp; u16* qs3; u16* k3; u16* vt; int mode;
  __device__ void operator()(int r, int c, float v) const {
    if (mode == 0) {
      v += bp[c];
      u16 h = f2bf(v);
      u16 l = f2bf(v - bf2f(h));
      if (c < 1024) {                     // q: A-side [hi|lo|hi]
        size_t b = (size_t)r * 3072 + c;
        qs3[b] = h; qs3[b + 1024] = l; qs3[b + 2048] = h;
      } else {                            // k: B-side [hi|hi|lo]
        size_t b = (size_t)r * 3072 + (c - 1024);
        k3[b] = h; k3[b + 1024] = h; k3[b + 2048] = l;
      }
    } else {                              // vt[r][c], r = Wv row, c = x row
      v += bp[2048 + r];
      vt[(size_t)r * 4096 + c] = f2bf(v); // coalesced in c (lane16)
    }
  }
};

struct EpiQCS {       // merged G2/S epilogue
  u16* qc3; u16* Sc; int isS;
  __device__ void operator()(int r, int c, float v) const {
    if (isS) {
      Sc[(size_t)r * 4096 + c] = f2bf(v);
    } else {
      u16 h = f2bf(v);
      u16 l = f2bf(v - bf2f(h));
      size_t b = (size_t)r * 3072 + c;
      qc3[b] = h; qc3[b + 1024] = l; qc3[b + 2048] = h;
    }
  }
};

struct EpiCL {        // CL: straight-through mask bit from fp32 accumulator
  u8* st; float b0;
  __device__ void operator()(int r, int c, float v) const {
    st[(size_t)r * 4096 + c] = (v + b0 > 0.f) ? 1 : 0;
  }
};

struct EpiPart {      // G4 split-K: plain partial store
  float* part;
  __device__ void operator()(int r, int c, float v) const {
    part[(size_t)r * 1024 + c] = v;
  }
};

template <class Epi>
__device__ __forceinline__ void gemm_core(
    const u16* __restrict__ A, const u16* __restrict__ B,
    int lda, int ldb, int K, int mBase, int nBase, Epi epi) {
  __shared__ __align__(16) u16 lA[128 * 64];
  __shared__ __align__(16) u16 lB[128 * 64];
  const int tid = threadIdx.x;
  const int wave = tid >> 6, lane = tid & 63;
  const int wm = wave & 1, wn = wave >> 1;
  const int lane16 = lane & 15, quad = lane >> 4;

  // staging: thread t stages rows (t>>3)+32i, phys slot (t&7),
  // global chunk = (t&7) ^ (row&7)   (row&7 invariant under +32)
  const int srow = tid >> 3;
  const int gchunk = ((tid & 7) ^ (srow & 7)) * 8;
  const u16* aP = A + (size_t)(mBase + srow) * lda + gchunk;
  const u16* bP = B + (size_t)(nBase + srow) * ldb + gchunk;
  const int woff = wave * 1024;   // issue i covers rows [32i,32i+32)

  const int rsw = lane16 & 7;
  const u16* raB = lA + (wm * 64 + lane16) * 64;
  const u16* rbB = lB + (wn * 64 + lane16) * 64;

  f32x4 acc[4][4];
#pragma unroll
  for (int i = 0; i < 4; i++)
#pragma unroll
    for (int j = 0; j < 4; j++) acc[i][j] = (f32x4){0.f, 0.f, 0.f, 0.f};

  for (int k0 = 0; k0 < K; k0 += 64) {
#pragma unroll
    for (int i = 0; i < 4; i++) {
      gld16((char*)lA + i * 4096 + woff, aP + (size_t)(32 * i) * lda + k0);
      gld16((char*)lB + i * 4096 + woff, bP + (size_t)(32 * i) * ldb + k0);
    }
    __syncthreads();
    short8 af[2][4], bfr[2][4];
#pragma unroll
    for (int s = 0; s < 2; s++) {
      const int sl = (((s << 2) + quad) ^ rsw) * 8;
#pragma unroll
      for (int j = 0; j < 4; j++) {
        af[s][j]  = *(const short8*)(raB + j * 1024 + sl);
        bfr[s][j] = *(const short8*)(rbB + j * 1024 + sl);
      }
    }
#pragma unroll
    for (int s = 0; s < 2; s++)
#pragma unroll
      for (int im = 0; im < 4; im++)
#pragma unroll
        for (int in = 0; in < 4; in++)
          acc[im][in] = __builtin_amdgcn_mfma_f32_16x16x32_bf16(
              af[s][im], bfr[s][in], acc[im][in], 0, 0, 0);
    __syncthreads();
  }

#pragma unroll
  for (int im = 0; im < 4; im++)
#pragma unroll
    for (int in = 0; in < 4; in++)
#pragma unroll
      for (int i = 0; i < 4; i++) {
        int r = mBase + wm * 64 + im * 16 + quad * 4 + i;
        int c = nBase + wn * 64 + in * 16 + lane16;
        epi(r, c, acc[im][in][i]);
      }
}

// G1, 1-D grid of 768, long blocks first:
//   bid<512:  q,k = xs3@W3^T (K=3072), nBase=(bid&15)*128, mBase=(bid>>4)*128
//   bid>=512: vt = Wv_hi@x_hi^T (K=1024)
__global__ __launch_bounds__(256, 2) void gemm_g1(
    const u16* __restrict__ xs3, const u16* __restrict__ W3,
    const float* __restrict__ bp, u16* __restrict__ qs3,
    u16* __restrict__ k3, u16* __restrict__ vt) {
  const int bid = blockIdx.x;
  if (bid < 512) {
    gemm_core(xs3, W3, 3072, 3072, 3072, (bid >> 4) * 128, (bid & 15) * 128,
              EpiG1{bp, qs3, k3, vt, 0});
  } else {
    const int t = bid - 512;   // 256 blocks: M=1024 (x8), N=4096 (x32)
    gemm_core(W3 + (size_t)2048 * 3072, xs3, 3072, 3072, 1024,
              (t & 7) * 128, (t >> 3) * 128, EpiG1{bp, qs3, k3, vt, 1});
  }
}

// merged G2/S, 1-D grid of 1280, long blocks first:
//   bid<256:  qc = qs3@C3^T (K=3072), nBase=(bid&7)*128, mBase=(bid>>3)*128
//   bid>=256: S = q_hi@k_hi^T (K=1024)
__global__ __launch_bounds__(256, 2) void gemm_qc_s(
    const u16* __restrict__ qs3, const u16* __restrict__ C3,
    const u16* __restrict__ k3, u16* __restrict__ qc3, u16* __restrict__ Sc) {
  const int bid = blockIdx.x;
  if (bid < 256) {
    gemm_core(qs3, C3, 3072, 3072, 3072, (bid >> 3) * 128, (bid & 7) * 128,
              EpiQCS{qc3, Sc, 0});
  } else {
    const int t = bid - 256;   // 1024 blocks: N=4096 (x32), M=4096 (x32)
    gemm_core(qs3, k3, 3072, 3072, 1024, (t >> 5) * 128, (t & 31) * 128,
              EpiQCS{qc3, Sc, 1});
  }
}

// CL = qc3 @ k3^T (K=3072) -> st bits
__global__ __launch_bounds__(256, 2) void gemm_cl(
    const u16* __restrict__ qc3, const u16* __restrict__ k3,
    const float* __restrict__ bias, u8* __restrict__ st) {
  gemm_core(qc3, k3, 3072, 3072, 3072, blockIdx.y * 128, blockIdx.x * 128,
            EpiCL{st, bias[0]});
}

// G4 split-K=2: z-slice does K in [2048z, 2048z+2048) -> parts[z]
__global__ __launch_bounds__(256, 2) void gemm_pv(
    const u16* __restrict__ P, const u16* __restrict__ vt,
    float* __restrict__ parts) {
  const size_t kOff = (size_t)blockIdx.z * 2048;
  gemm_core(P + kOff, vt + kOff, 4096, 4096, 2048,
            blockIdx.y * 128, blockIdx.x * 128,
            EpiPart{parts + (size_t)blockIdx.z * 4096 * 1024});
}

// out = (1-bm)*x + bm*(p0 + p1)
__global__ void reduce_out(const float* __restrict__ x, const float* __restrict__ bm,
                           const float* __restrict__ parts, float* __restrict__ out) {
  int id = blockIdx.x * 256 + threadIdx.x;
  int flat = id * 4;
  int r = flat >> 10;
  float b = bm[r];
  f4v xv = *(const f4v*)(x + (size_t)flat);
  f4v p0 = *(const f4v*)(parts + (size_t)flat);
  f4v p1 = *(const f4v*)(parts + (size_t)4096 * 1024 + flat);
  f4v o;
#pragma unroll
  for (int e = 0; e < 4; e++) o[e] = b * (p0[e] + p1[e]) + (1.0f - b) * xv[e];
  *(f4v*)(out + (size_t)flat) = o;
}

// ---------------- mask + softmax ----------------
// logits = S/32 - 10000*(1 - am - st*lm); P = softmax(row).
__global__ __launch_bounds__(256) void mask_softmax(
    const u16* __restrict__ Sc, const u8* __restrict__ st,
    const float* __restrict__ am, const float* __restrict__ lm,
    u16* __restrict__ P) {
  const int n = blockIdx.x, tid = threadIdx.x;
  const int lane = tid & 63, wave = tid >> 6;
  const u16* Srow = Sc + (size_t)n * 4096;
  const u8* Trow = st + (size_t)n * 4096;
  const float* Arow = am + (size_t)n * 4096;
  const float* Lrow = lm + (size_t)n * 4096;

  float lg[16];
  float mx = -3.4e38f;
#pragma unroll
  for (int j = 0; j < 2; j++) {
    int base = (tid + 256 * j) * 8;
    u16x8 s8 = *(const u16x8*)(Srow + base);
    unsigned long long t8 = *(const unsigned long long*)(Trow + base);
    f4v a0 = *(const f4v*)(Arow + base), a1 = *(const f4v*)(Arow + base + 4);
    f4v l0 = *(const f4v*)(Lrow + base), l1 = *(const f4v*)(Lrow + base + 4);
#pragma unroll
    for (int e = 0; e < 8; e++) {
      float stv = ((t8 >> (8 * e)) & 1ull) ? 1.f : 0.f;
      float a = (e < 4) ? a0[e] : a1[e - 4];
      float l = (e < 4) ? l0[e] : l1[e - 4];
      float mv = a + stv * l;
      float v = bf2f(s8[e]) * 0.03125f - 10000.f * (1.f - mv);
      lg[j * 8 + e] = v;
      mx = fmaxf(mx, v);
    }
  }
#pragma unroll
  for (int o = 32; o; o >>= 1) mx = fmaxf(mx, __shfl_xor(mx, o));
  __shared__ float smax[4], ssum[4];
  if (lane == 0) smax[wave] = mx;
  __syncthreads();
  mx = fmaxf(fmaxf(smax[0], smax[1]), fmaxf(smax[2], smax[3]));

  float sum = 0.f;
#pragma unroll
  for (int i = 0; i < 16; i++) { lg[i] = __expf(lg[i] - mx); sum += lg[i]; }
#pragma unroll
  for (int o = 32; o; o >>= 1) sum += __shfl_xor(sum, o);
  if (lane == 0) ssum[wave] = sum;
  __syncthreads();
  float inv = 1.f / (ssum[0] + ssum[1] + ssum[2] + ssum[3]);

  u16* Pr = P + (size_t)n * 4096;
#pragma unroll
  for (int j = 0; j < 2; j++) {
    int base = (tid + 256 * j) * 8;
    u16x8 o8;
#pragma unroll
    for (int e = 0; e < 8; e++) o8[e] = f2bf(lg[j * 8 + e] * inv);
    *(u16x8*)(Pr + base) = o8;
  }
}

// ---------------- launch ----------------

extern "C" void kernel_launch(void* const* d_in, const int* in_sizes, int n_in,
                              void* d_out, int out_size, void* d_ws, size_t ws_size,
                              hipStream_t stream) {
  const float* x    = (const float*)d_in[0];
  const float* am   = (const float*)d_in[1];
  const float* lm   = (const float*)d_in[2];
  const float* bm   = (const float*)d_in[3];
  const float* Wq   = (const float*)d_in[4];
  const float* bq   = (const float*)d_in[5];
  const float* Wk   = (const float*)d_in[6];
  const float* bk   = (const float*)d_in[7];
  const float* Wv   = (const float*)d_in[8];
  const float* bv   = (const float*)d_in[9];
  const float* Cc   = (const float*)d_in[10];
  const float* bias = (const float*)d_in[11];
  float* out = (float*)d_out;
  char* ws = (char*)d_ws;

  if (ws_size < 0xB010000) return;  // ~176 MB scratch

  u16*  xs3 = (u16*) (ws + 0x0000000);  // 24 MB [x_hi|x_lo|x_hi]
  u16*  W3  = (u16*) (ws + 0x1800000);  // 18 MB [W_hi|W_hi|W_lo]
  u16*  C3  = (u16*) (ws + 0x2A00000);  //  6 MB [Ct_hi|Ct_hi|Ct_lo]
  float* bp = (float*)(ws + 0x3000000); // 12 KB
  u16*  qs3 = (u16*) (ws + 0x3010000);  // 24 MB [q_hi|q_lo|q_hi]
  u16*  qc3 = (u16*) (ws + 0x4810000);  // 24 MB [qc_hi|qc_lo|qc_hi]
  u16*  k3  = (u16*) (ws + 0x6010000);  // 24 MB [k_hi|k_hi|k_lo]
  u16*  vt  = (u16*) (ws + 0x7810000);  //  8 MB v^T [1024,4096]
  u16*  Sc  = (u16*) (ws + 0x8010000);  // 32 MB bf16 S
  u8*   st  = (u8*)  (ws + 0xA010000);  // 16 MB straight-through bits
  u16*  P   = (u16*) (ws + 0x0000000);  // 32 MB overlay (xs3/W3-head dead)
  float* parts = (float*)(ws + 0x4810000); // 32 MB overlay (qc3/k3-head dead)

  prep_x   <<<4096, 256, 0, stream>>>(x, xs3);
  prep_w   <<<3072, 256, 0, stream>>>(Wq, Wk, Wv, W3);
  prep_bias<<<12,   256, 0, stream>>>(bq, bk, bv, bp);
  prep_c   <<<dim3(32, 32), 256, 0, stream>>>(Cc, C3);

  // G1: q,k = xs3 @ W3^T (K=3072, bid<512) | vt = Wv@x^T (K=1024, bid>=512)
  gemm_g1<<<768, 256, 0, stream>>>(xs3, W3, bp, qs3, k3, vt);
  // merged: qc = qs3 @ C3^T (K=3072, bid<256) | S = q_hi @ k_hi^T (K=1024)
  gemm_qc_s<<<1280, 256, 0, stream>>>(qs3, C3, k3, qc3, Sc);
  // CL = qc3 @ k3^T (K=3072) -> st bits
  gemm_cl<<<dim3(32, 32), 256, 0, stream>>>(qc3, k3, bias, st);
  // mask + softmax -> P (bf16)
  mask_softmax<<<4096, 256, 0, stream>>>(Sc, st, am, lm, P);
  // G4: parts[z] = P @ vt^T over K-halves (plain stores, no atomics)
  gemm_pv<<<dim3(8, 32, 2), 256, 0, stream>>>(P, vt, parts);
  // out = (1-bm)x + bm*(p0+p1)
  reduce_out<<<4096, 256, 0, stream>>>(x, bm, parts, out);
}